// Round 5
// baseline (246.689 us; speedup 1.0000x reference)
//
#include <hip/hip_runtime.h>
#include <math.h>

#define PI_F 3.14159265358979323846f

// ---------------- fast device math ----------------
__device__ __forceinline__ float sigm_f(float x) {
    return __fdividef(1.0f, 1.0f + __expf(-x));
}
__device__ __forceinline__ float tanh_f(float x) {
    float xc = fminf(fmaxf(x, -9.0f), 9.0f);
    float e = __expf(2.0f * xc);
    return 1.0f - __fdividef(2.0f, e + 1.0f);
}

// ---------------- macro lists ----------------
#define AP16(M) M(0) M(1) M(2) M(3) M(4) M(5) M(6) M(7) M(8) M(9) M(10) M(11) M(12) M(13) M(14) M(15)
#define AP64(M) AP16(M) M(16) M(17) M(18) M(19) M(20) M(21) M(22) M(23) \
  M(24) M(25) M(26) M(27) M(28) M(29) M(30) M(31) M(32) M(33) M(34) M(35) \
  M(36) M(37) M(38) M(39) M(40) M(41) M(42) M(43) M(44) M(45) M(46) M(47) \
  M(48) M(49) M(50) M(51) M(52) M(53) M(54) M(55) M(56) M(57) M(58) M(59) \
  M(60) M(61) M(62) M(63)
#define APQ16(M) M(0,1,2,3) M(4,5,6,7) M(8,9,10,11) M(12,13,14,15) \
  M(16,17,18,19) M(20,21,22,23) M(24,25,26,27) M(28,29,30,31) \
  M(32,33,34,35) M(36,37,38,39) M(40,41,42,43) M(44,45,46,47) \
  M(48,49,50,51) M(52,53,54,55) M(56,57,58,59) M(60,61,62,63)

// ============================================================
// Kernel 1: 2-layer GRU over reversed action sequence + encoder head.
// ============================================================
__global__ __launch_bounds__(128)
void gru_kernel(const float* __restrict__ act,
                const float* __restrict__ Wih0, const float* __restrict__ Whh0,
                const float* __restrict__ bih0, const float* __restrict__ bhh0,
                const float* __restrict__ Wih1, const float* __restrict__ Whh1,
                const float* __restrict__ bih1, const float* __restrict__ bhh1,
                const float* __restrict__ encW, const float* __restrict__ encb,
                float* __restrict__ p_out)
{
    __shared__ float wih0_l[6 * 96];
    __shared__ float whh0_l[32 * 96];
    __shared__ float wih1_l[32 * 96];
    __shared__ float whh1_l[32 * 96];
    __shared__ float enc_l[64];
    __shared__ float xbuf[4 * 32 * 6];
    __shared__ float hbuf0[4][32];
    __shared__ float hbuf1[4][32];

    const int tid = threadIdx.x;

    for (int idx = tid; idx < 96 * 6; idx += 128) {
        int r = idx / 6, c = idx - r * 6;
        wih0_l[c * 96 + (r & 31) * 3 + (r >> 5)] = Wih0[idx];
    }
    for (int idx = tid; idx < 96 * 32; idx += 128) {
        int r = idx >> 5, c = idx & 31;
        int d = c * 96 + (r & 31) * 3 + (r >> 5);
        whh0_l[d] = Whh0[idx];
        wih1_l[d] = Wih1[idx];
        whh1_l[d] = Whh1[idx];
    }
    if (tid < 64) {
        int o = tid >> 5, j = tid & 31;
        enc_l[j * 2 + o] = encW[o * 32 + j];
    }
    {
        const float inv3 = (1.0f / 3.0f);
        int base = blockIdx.x * (4 * 32 * 6);
        for (int idx = tid; idx < 4 * 32 * 6; idx += 128)
            xbuf[idx] = act[base + idx] * inv3;
    }
    __syncthreads();

    const int s = tid >> 5;
    const int j = tid & 31;
    const int b = blockIdx.x * 4 + s;
    const int j3 = j * 3;

    const float bi0r = bih0[j], bi0z = bih0[32 + j], bi0n = bih0[64 + j];
    const float bh0r = bhh0[j], bh0z = bhh0[32 + j], bh0n = bhh0[64 + j];
    const float bi1r = bih1[j], bi1z = bih1[32 + j], bi1n = bih1[64 + j];
    const float bh1r = bhh1[j], bh1z = bhh1[32 + j], bh1n = bhh1[64 + j];

    float* hb0 = &hbuf0[s][0];
    float* hb1 = &hbuf1[s][0];
    hb0[j] = 0.0f;
    hb1[j] = 0.0f;
    float h0 = 0.0f, h1 = 0.0f;
    const float* xs = &xbuf[s * 192];

    for (int t = 0; t < 32; ++t) {
        const float* xt = &xs[(31 - t) * 6];

        float ar = bi0r, az = bi0z, an = bi0n;
        #pragma unroll
        for (int d = 0; d < 6; ++d) {
            float xv = xt[d];
            const float* w = &wih0_l[d * 96 + j3];
            ar = fmaf(xv, w[0], ar); az = fmaf(xv, w[1], az); an = fmaf(xv, w[2], an);
        }
        float gr0 = bh0r, gz0 = bh0z, gn0 = bh0n;
        float gr1 = 0.0f, gz1 = 0.0f, gn1 = 0.0f;
        #pragma unroll
        for (int i = 0; i < 32; i += 2) {
            float hi0 = hb0[i], hi1 = hb0[i + 1];
            const float* w0 = &whh0_l[i * 96 + j3];
            const float* w1 = &whh0_l[(i + 1) * 96 + j3];
            gr0 = fmaf(hi0, w0[0], gr0); gz0 = fmaf(hi0, w0[1], gz0); gn0 = fmaf(hi0, w0[2], gn0);
            gr1 = fmaf(hi1, w1[0], gr1); gz1 = fmaf(hi1, w1[1], gz1); gn1 = fmaf(hi1, w1[2], gn1);
        }
        float r = sigm_f(ar + gr0 + gr1);
        float z = sigm_f(az + gz0 + gz1);
        float n = tanh_f(an + r * (gn0 + gn1));
        h0 = (1.0f - z) * n + z * h0;
        hb0[j] = h0;

        float a1r0 = bi1r, a1z0 = bi1z, a1n0 = bi1n;
        float a1r1 = 0.0f, a1z1 = 0.0f, a1n1 = 0.0f;
        #pragma unroll
        for (int i = 0; i < 32; i += 2) {
            float hi0 = hb0[i], hi1 = hb0[i + 1];
            const float* w0 = &wih1_l[i * 96 + j3];
            const float* w1 = &wih1_l[(i + 1) * 96 + j3];
            a1r0 = fmaf(hi0, w0[0], a1r0); a1z0 = fmaf(hi0, w0[1], a1z0); a1n0 = fmaf(hi0, w0[2], a1n0);
            a1r1 = fmaf(hi1, w1[0], a1r1); a1z1 = fmaf(hi1, w1[1], a1z1); a1n1 = fmaf(hi1, w1[2], a1n1);
        }
        float g1r0 = bh1r, g1z0 = bh1z, g1n0 = bh1n;
        float g1r1 = 0.0f, g1z1 = 0.0f, g1n1 = 0.0f;
        #pragma unroll
        for (int i = 0; i < 32; i += 2) {
            float hi0 = hb1[i], hi1 = hb1[i + 1];
            const float* w0 = &whh1_l[i * 96 + j3];
            const float* w1 = &whh1_l[(i + 1) * 96 + j3];
            g1r0 = fmaf(hi0, w0[0], g1r0); g1z0 = fmaf(hi0, w0[1], g1z0); g1n0 = fmaf(hi0, w0[2], g1n0);
            g1r1 = fmaf(hi1, w1[0], g1r1); g1z1 = fmaf(hi1, w1[1], g1z1); g1n1 = fmaf(hi1, w1[2], g1n1);
        }
        float r1 = sigm_f(a1r0 + a1r1 + g1r0 + g1r1);
        float z1 = sigm_f(a1z0 + a1z1 + g1z0 + g1z1);
        float n1 = tanh_f(a1n0 + a1n1 + r1 * (g1n0 + g1n1));
        h1 = (1.0f - z1) * n1 + z1 * h1;
        hb1[j] = h1;
    }

    float v0 = h1 * enc_l[j * 2 + 0];
    float v1 = h1 * enc_l[j * 2 + 1];
    #pragma unroll
    for (int off = 16; off > 0; off >>= 1) {
        v0 += __shfl_xor(v0, off, 32);
        v1 += __shfl_xor(v1, off, 32);
    }
    if (j == 0) {
        p_out[b * 2 + 0] = v0 + encb[0];
        p_out[b * 2 + 1] = v1 + encb[1];
    }
}

// ============================================================
// Kernel 2: per-(b,t) MLP + Laplace series. Named-VGPR activations,
// wave-uniform (SGPR) weights via readfirstlane(wave-id).
// ============================================================
__global__ __launch_bounds__(256, 2)
void mlp_kernel(const float* __restrict__ obs, const float* __restrict__ ts,
                const float* __restrict__ p_act,
                const float* __restrict__ W1, const float* __restrict__ b1,
                const float* __restrict__ W2, const float* __restrict__ b2,
                const float* __restrict__ W3, const float* __restrict__ b3,
                float* __restrict__ out)
{
    __shared__ float h1_lds[64 * 64];
    __shared__ float h2_lds[64 * 64];
    __shared__ float f_lds[4 * 64 * 17];
    __shared__ float scale_lds[64];

    const int tid = threadIdx.x;
    const int wq = __builtin_amdgcn_readfirstlane(tid >> 6);  // wave id (SGPR)
    const int l = tid & 63;
    const int item = blockIdx.x * 64 + l;
    const int b = item >> 4;
    const int obase = wq * 16;

    const float t = ts[item];
    const float rTc = __fdividef(0.5f, t);
    const float gamma = 0.001f + 4.6051701859880913680f * rTc;  // -ln(0.01)/Tc

    if (wq == 3) scale_lds[l] = __expf(gamma * t) * rTc;

    // ---- H1: i-outer, theta/phi on the fly, 16 named accumulators ----
    const float gam2 = gamma * gamma;
    const float rg = __fdividef(1.0f, gamma);
    const float pirTc = PI_F * rTc;

    #define DECL_ACC(o) float acc##o = b1[obase + o];
    AP16(DECL_ACC)
    #undef DECL_ACC

    {
        const float* wth = W1 + obase * 85;
        float fk = 0.0f;
        for (int k = 0; k < 33; ++k) {
            float sim = fk * pirTc;
            float vth = atanf(sim * rg);
            float sq = fmaf(sim, sim, gam2);
            float vph = asinf(__fdividef(sq - 1.0f, sq + 1.0f));
            const float* ct = wth + k;
            const float* cp = wth + 33 + k;
            #define H1C(o) acc##o = fmaf(vth, ct[(o) * 85], acc##o); \
                           acc##o = fmaf(vph, cp[(o) * 85], acc##o);
            AP16(H1C)
            #undef H1C
            fk += 1.0f;
        }
        const float* cpp = wth + 66;
        #pragma unroll
        for (int j = 0; j < 19; ++j) {
            float pv = (j < 17) ? obs[b * 17 + j] : p_act[b * 2 + (j - 17)];
            #define H1P(o) acc##o = fmaf(pv, cpp[(o) * 85 + j], acc##o);
            AP16(H1P)
            #undef H1P
        }
    }
    #define H1S(o) h1_lds[(obase + (o)) * 64 + l] = tanh_f(acc##o);
    AP16(H1S)
    #undef H1S
    __syncthreads();

    // ---- H2: h1 in 64 named regs ----
    {
        #define DH(i) float h##i = h1_lds[(i) * 64 + l];
        AP64(DH)
        #undef DH
        asm volatile("" : "+v"(h0),"+v"(h1),"+v"(h2),"+v"(h3),"+v"(h4),"+v"(h5),"+v"(h6),"+v"(h7),
                          "+v"(h8),"+v"(h9),"+v"(h10),"+v"(h11),"+v"(h12),"+v"(h13),"+v"(h14),"+v"(h15));
        asm volatile("" : "+v"(h16),"+v"(h17),"+v"(h18),"+v"(h19),"+v"(h20),"+v"(h21),"+v"(h22),"+v"(h23),
                          "+v"(h24),"+v"(h25),"+v"(h26),"+v"(h27),"+v"(h28),"+v"(h29),"+v"(h30),"+v"(h31));
        asm volatile("" : "+v"(h32),"+v"(h33),"+v"(h34),"+v"(h35),"+v"(h36),"+v"(h37),"+v"(h38),"+v"(h39),
                          "+v"(h40),"+v"(h41),"+v"(h42),"+v"(h43),"+v"(h44),"+v"(h45),"+v"(h46),"+v"(h47));
        asm volatile("" : "+v"(h48),"+v"(h49),"+v"(h50),"+v"(h51),"+v"(h52),"+v"(h53),"+v"(h54),"+v"(h55),
                          "+v"(h56),"+v"(h57),"+v"(h58),"+v"(h59),"+v"(h60),"+v"(h61),"+v"(h62),"+v"(h63));

        for (int oo = 0; oo < 16; ++oo) {
            const float* wr = W2 + (obase + oo) * 64;
            float ac0 = b2[obase + oo], ac1 = 0.0f, ac2 = 0.0f, ac3 = 0.0f;
            #define H2Q(i0,i1,i2,i3) ac0 = fmaf(h##i0, wr[i0], ac0); ac1 = fmaf(h##i1, wr[i1], ac1); \
                                     ac2 = fmaf(h##i2, wr[i2], ac2); ac3 = fmaf(h##i3, wr[i3], ac3);
            APQ16(H2Q)
            #undef H2Q
            h2_lds[(obase + oo) * 64 + l] = tanh_f((ac0 + ac1) + (ac2 + ac3));
        }
    }
    __syncthreads();

    // ---- W3 + series epilogue for k ≡ wq (mod 4) ----
    {
        #define DG(i) float g##i = h2_lds[(i) * 64 + l];
        AP64(DG)
        #undef DG
        asm volatile("" : "+v"(g0),"+v"(g1),"+v"(g2),"+v"(g3),"+v"(g4),"+v"(g5),"+v"(g6),"+v"(g7),
                          "+v"(g8),"+v"(g9),"+v"(g10),"+v"(g11),"+v"(g12),"+v"(g13),"+v"(g14),"+v"(g15));
        asm volatile("" : "+v"(g16),"+v"(g17),"+v"(g18),"+v"(g19),"+v"(g20),"+v"(g21),"+v"(g22),"+v"(g23),
                          "+v"(g24),"+v"(g25),"+v"(g26),"+v"(g27),"+v"(g28),"+v"(g29),"+v"(g30),"+v"(g31));
        asm volatile("" : "+v"(g32),"+v"(g33),"+v"(g34),"+v"(g35),"+v"(g36),"+v"(g37),"+v"(g38),"+v"(g39),
                          "+v"(g40),"+v"(g41),"+v"(g42),"+v"(g43),"+v"(g44),"+v"(g45),"+v"(g46),"+v"(g47));
        asm volatile("" : "+v"(g48),"+v"(g49),"+v"(g50),"+v"(g51),"+v"(g52),"+v"(g53),"+v"(g54),"+v"(g55),
                          "+v"(g56),"+v"(g57),"+v"(g58),"+v"(g59),"+v"(g60),"+v"(g61),"+v"(g62),"+v"(g63));

        const float csgn = (wq == 1 || wq == 2) ? -1.0f : 1.0f;
        for (int o = 0; o < 17; ++o) {
            float facc = 0.0f;
            for (int k = wq; k < 33; k += 4) {
                const int rt = o * 33 + k;
                const float* wt = W3 + rt * 64;
                const float* wp = W3 + (rt + 561) * 64;
                float at0 = 0.0f, at1 = 0.0f, at2 = 0.0f, at3 = 0.0f;
                float ap0 = 0.0f, ap1 = 0.0f, ap2 = 0.0f, ap3 = 0.0f;
                #define W3Q(i0,i1,i2,i3) \
                    at0 = fmaf(g##i0, wt[i0], at0); ap0 = fmaf(g##i0, wp[i0], ap0); \
                    at1 = fmaf(g##i1, wt[i1], at1); ap1 = fmaf(g##i1, wp[i1], ap1); \
                    at2 = fmaf(g##i2, wt[i2], at2); ap2 = fmaf(g##i2, wp[i2], ap2); \
                    at3 = fmaf(g##i3, wt[i3], at3); ap3 = fmaf(g##i3, wp[i3], ap3);
                APQ16(W3Q)
                #undef W3Q
                float at = b3[rt] + ((at0 + at1) + (at2 + at3));
                float ap = b3[rt + 561] + ((ap0 + ap1) + (ap2 + ap3));
                float theta = tanh_f(at) * PI_F;
                float phi   = tanh_f(ap) * (0.5f * PI_F);
                float sph = __sinf(phi), cph = __cosf(phi);
                float rd = __fdividef(1.0f, 1.0f - sph);
                float tr = (wq == 0 || wq == 2) ? __cosf(theta) : __sinf(theta);
                float wk = (k == 0) ? 0.5f : 1.0f;
                facc = fmaf(csgn * wk, tr * cph * rd, facc);
            }
            f_lds[(wq * 64 + l) * 17 + o] = facc;
        }
    }
    __syncthreads();

    // ---- reduce 4 k-class partials, scale, write out ----
    const int base_item = blockIdx.x * 64;
    for (int idx = tid; idx < 64 * 17; idx += 256) {
        const int li = idx / 17;
        const int o  = idx - li * 17;
        float tot = f_lds[li * 17 + o] + f_lds[(64 + li) * 17 + o]
                  + f_lds[(128 + li) * 17 + o] + f_lds[(192 + li) * 17 + o];
        out[(base_item + li) * 17 + o] = tot * scale_lds[li];
    }
}

extern "C" void kernel_launch(void* const* d_in, const int* in_sizes, int n_in,
                              void* d_out, int out_size, void* d_ws, size_t ws_size,
                              hipStream_t stream) {
    (void)in_sizes; (void)n_in; (void)out_size; (void)ws_size;
    const float* obs  = (const float*)d_in[0];
    const float* act  = (const float*)d_in[1];
    const float* ts   = (const float*)d_in[2];
    const float* Wih0 = (const float*)d_in[3];
    const float* Whh0 = (const float*)d_in[4];
    const float* bih0 = (const float*)d_in[5];
    const float* bhh0 = (const float*)d_in[6];
    const float* Wih1 = (const float*)d_in[7];
    const float* Whh1 = (const float*)d_in[8];
    const float* bih1 = (const float*)d_in[9];
    const float* bhh1 = (const float*)d_in[10];
    const float* encW = (const float*)d_in[11];
    const float* encb = (const float*)d_in[12];
    const float* W1   = (const float*)d_in[13];
    const float* b1   = (const float*)d_in[14];
    const float* W2   = (const float*)d_in[15];
    const float* b2   = (const float*)d_in[16];
    const float* W3   = (const float*)d_in[17];
    const float* b3   = (const float*)d_in[18];
    float* o_ptr  = (float*)d_out;
    float* p_act  = (float*)d_ws;

    gru_kernel<<<dim3(512), dim3(128), 0, stream>>>(
        act, Wih0, Whh0, bih0, bhh0, Wih1, Whh1, bih1, bhh1, encW, encb, p_act);
    mlp_kernel<<<dim3(512), dim3(256), 0, stream>>>(
        obs, ts, p_act, W1, b1, W2, b2, W3, b3, o_ptr);
}

// Round 6
// 221.101 us; speedup vs baseline: 1.1157x; 1.1157x over previous
//
#include <hip/hip_runtime.h>
#include <math.h>

#define PI_F 3.14159265358979323846f

// ---------------- fast device math ----------------
__device__ __forceinline__ float sigm_f(float x) {
    return __fdividef(1.0f, 1.0f + __expf(-x));
}
__device__ __forceinline__ float tanh_f(float x) {
    float xc = fminf(fmaxf(x, -9.0f), 9.0f);
    float e = __expf(2.0f * xc);
    return 1.0f - __fdividef(2.0f, e + 1.0f);
}

// ============================================================
// Kernel 1: 2-layer GRU over reversed action sequence + encoder head.
// 128 threads = 4 samples x 32 hidden-lanes. Weights staged to LDS
// transposed + gate-interleaved: w[input][unit*3 + gate].
// ============================================================
__global__ __launch_bounds__(128)
void gru_kernel(const float* __restrict__ act,
                const float* __restrict__ Wih0, const float* __restrict__ Whh0,
                const float* __restrict__ bih0, const float* __restrict__ bhh0,
                const float* __restrict__ Wih1, const float* __restrict__ Whh1,
                const float* __restrict__ bih1, const float* __restrict__ bhh1,
                const float* __restrict__ encW, const float* __restrict__ encb,
                float* __restrict__ p_out)
{
    __shared__ float wih0_l[6 * 96];
    __shared__ float whh0_l[32 * 96];
    __shared__ float wih1_l[32 * 96];
    __shared__ float whh1_l[32 * 96];
    __shared__ float enc_l[64];
    __shared__ float xbuf[4 * 32 * 6];
    __shared__ float hbuf0[4][32];
    __shared__ float hbuf1[4][32];

    const int tid = threadIdx.x;

    for (int idx = tid; idx < 96 * 6; idx += 128) {
        int r = idx / 6, c = idx - r * 6;
        wih0_l[c * 96 + (r & 31) * 3 + (r >> 5)] = Wih0[idx];
    }
    for (int idx = tid; idx < 96 * 32; idx += 128) {
        int r = idx >> 5, c = idx & 31;
        int d = c * 96 + (r & 31) * 3 + (r >> 5);
        whh0_l[d] = Whh0[idx];
        wih1_l[d] = Wih1[idx];
        whh1_l[d] = Whh1[idx];
    }
    if (tid < 64) {
        int o = tid >> 5, j = tid & 31;
        enc_l[j * 2 + o] = encW[o * 32 + j];
    }
    {
        const float inv3 = (1.0f / 3.0f);
        int base = blockIdx.x * (4 * 32 * 6);
        for (int idx = tid; idx < 4 * 32 * 6; idx += 128)
            xbuf[idx] = act[base + idx] * inv3;
    }
    __syncthreads();

    const int s = tid >> 5;
    const int j = tid & 31;
    const int b = blockIdx.x * 4 + s;
    const int j3 = j * 3;

    const float bi0r = bih0[j], bi0z = bih0[32 + j], bi0n = bih0[64 + j];
    const float bh0r = bhh0[j], bh0z = bhh0[32 + j], bh0n = bhh0[64 + j];
    const float bi1r = bih1[j], bi1z = bih1[32 + j], bi1n = bih1[64 + j];
    const float bh1r = bhh1[j], bh1z = bhh1[32 + j], bh1n = bhh1[64 + j];

    float* hb0 = &hbuf0[s][0];
    float* hb1 = &hbuf1[s][0];
    hb0[j] = 0.0f;
    hb1[j] = 0.0f;
    float h0 = 0.0f, h1 = 0.0f;
    const float* xs = &xbuf[s * 192];

    for (int t = 0; t < 32; ++t) {
        const float* xt = &xs[(31 - t) * 6];

        float ar = bi0r, az = bi0z, an = bi0n;
        #pragma unroll
        for (int d = 0; d < 6; ++d) {
            float xv = xt[d];
            const float* w = &wih0_l[d * 96 + j3];
            ar = fmaf(xv, w[0], ar); az = fmaf(xv, w[1], az); an = fmaf(xv, w[2], an);
        }
        float gr0 = bh0r, gz0 = bh0z, gn0 = bh0n;
        float gr1 = 0.0f, gz1 = 0.0f, gn1 = 0.0f;
        #pragma unroll
        for (int i = 0; i < 32; i += 2) {
            float hi0 = hb0[i], hi1 = hb0[i + 1];
            const float* w0 = &whh0_l[i * 96 + j3];
            const float* w1 = &whh0_l[(i + 1) * 96 + j3];
            gr0 = fmaf(hi0, w0[0], gr0); gz0 = fmaf(hi0, w0[1], gz0); gn0 = fmaf(hi0, w0[2], gn0);
            gr1 = fmaf(hi1, w1[0], gr1); gz1 = fmaf(hi1, w1[1], gz1); gn1 = fmaf(hi1, w1[2], gn1);
        }
        float r = sigm_f(ar + gr0 + gr1);
        float z = sigm_f(az + gz0 + gz1);
        float n = tanh_f(an + r * (gn0 + gn1));
        h0 = (1.0f - z) * n + z * h0;
        hb0[j] = h0;

        float a1r0 = bi1r, a1z0 = bi1z, a1n0 = bi1n;
        float a1r1 = 0.0f, a1z1 = 0.0f, a1n1 = 0.0f;
        #pragma unroll
        for (int i = 0; i < 32; i += 2) {
            float hi0 = hb0[i], hi1 = hb0[i + 1];
            const float* w0 = &wih1_l[i * 96 + j3];
            const float* w1 = &wih1_l[(i + 1) * 96 + j3];
            a1r0 = fmaf(hi0, w0[0], a1r0); a1z0 = fmaf(hi0, w0[1], a1z0); a1n0 = fmaf(hi0, w0[2], a1n0);
            a1r1 = fmaf(hi1, w1[0], a1r1); a1z1 = fmaf(hi1, w1[1], a1z1); a1n1 = fmaf(hi1, w1[2], a1n1);
        }
        float g1r0 = bh1r, g1z0 = bh1z, g1n0 = bh1n;
        float g1r1 = 0.0f, g1z1 = 0.0f, g1n1 = 0.0f;
        #pragma unroll
        for (int i = 0; i < 32; i += 2) {
            float hi0 = hb1[i], hi1 = hb1[i + 1];
            const float* w0 = &whh1_l[i * 96 + j3];
            const float* w1 = &whh1_l[(i + 1) * 96 + j3];
            g1r0 = fmaf(hi0, w0[0], g1r0); g1z0 = fmaf(hi0, w0[1], g1z0); g1n0 = fmaf(hi0, w0[2], g1n0);
            g1r1 = fmaf(hi1, w1[0], g1r1); g1z1 = fmaf(hi1, w1[1], g1z1); g1n1 = fmaf(hi1, w1[2], g1n1);
        }
        float r1 = sigm_f(a1r0 + a1r1 + g1r0 + g1r1);
        float z1 = sigm_f(a1z0 + a1z1 + g1z0 + g1z1);
        float n1 = tanh_f(a1n0 + a1n1 + r1 * (g1n0 + g1n1));
        h1 = (1.0f - z1) * n1 + z1 * h1;
        hb1[j] = h1;
    }

    float v0 = h1 * enc_l[j * 2 + 0];
    float v1 = h1 * enc_l[j * 2 + 1];
    #pragma unroll
    for (int off = 16; off > 0; off >>= 1) {
        v0 += __shfl_xor(v0, off, 32);
        v1 += __shfl_xor(v1, off, 32);
    }
    if (j == 0) {
        p_out[b * 2 + 0] = v0 + encb[0];
        p_out[b * 2 + 1] = v1 + encb[1];
    }
}

// ============================================================
// Kernel 2: per-(b,t) MLP + Laplace series.
// 512 threads = 8 waves; lane = item (64 items/block).
// Wave wq: H1/H2 outputs [wq*8, wq*8+8); W3 k-classes k ≡ wq (mod 8)
// (period-4 trig sign pattern is wave-uniform; wave 0 takes k=32 as a
// 5th pair). Activations in LDS transposed-chunked layout
// h[(i>>2)*256 + l*4 + (i&3)] -> consumer ds_read_b128, only 4 g +
// 8-10 accumulators live (no big register arrays, no spills).
// Weights wave-uniform -> scalar s_load path.
// ============================================================

// One o-row of the W3 epilogue: NP (theta,phi) row-pairs at rows
// rbase + 8*kk, dotted against this lane's 64 h2 values.
template<int NP, bool USE_SIN, bool K0HALF>
__device__ __forceinline__ float w3_o(const float* __restrict__ W3,
                                      const float* __restrict__ b3,
                                      const float* __restrict__ h2t,
                                      const int l4, const int rbase,
                                      const float csgn)
{
    float at[NP], ap[NP];
    #pragma unroll
    for (int kk = 0; kk < NP; ++kk) { at[kk] = 0.0f; ap[kk] = 0.0f; }
    #pragma unroll
    for (int c = 0; c < 16; ++c) {
        const float4 g4 = *reinterpret_cast<const float4*>(&h2t[c * 256 + l4]);
        const float gg[4] = {g4.x, g4.y, g4.z, g4.w};
        #pragma unroll
        for (int kk = 0; kk < NP; ++kk) {
            const float* wt = W3 + (rbase + 8 * kk) * 64 + c * 4;
            const float* wp = wt + 561 * 64;
            #pragma unroll
            for (int j = 0; j < 4; ++j) {
                at[kk] = fmaf(gg[j], wt[j], at[kk]);
                ap[kk] = fmaf(gg[j], wp[j], ap[kk]);
            }
        }
    }
    float facc = 0.0f;
    #pragma unroll
    for (int kk = 0; kk < NP; ++kk) {
        const int rt = rbase + 8 * kk;
        float a = at[kk] + b3[rt];
        float p = ap[kk] + b3[rt + 561];
        float theta = tanh_f(a) * PI_F;
        float phi   = tanh_f(p) * (0.5f * PI_F);
        float sph = __sinf(phi), cph = __cosf(phi);
        float rd = __fdividef(1.0f, 1.0f - sph);
        float tr = USE_SIN ? __sinf(theta) : __cosf(theta);
        float wk = (K0HALF && kk == 0) ? 0.5f : 1.0f;
        facc = fmaf(csgn * wk, tr * cph * rd, facc);
    }
    return facc;
}

__global__ __launch_bounds__(512, 4)
void mlp_kernel(const float* __restrict__ obs, const float* __restrict__ ts,
                const float* __restrict__ p_act,
                const float* __restrict__ W1, const float* __restrict__ b1,
                const float* __restrict__ W2, const float* __restrict__ b2,
                const float* __restrict__ W3, const float* __restrict__ b3,
                float* __restrict__ out)
{
    __shared__ __align__(16) float h1t[16 * 256];      // [i>>2][l][i&3]
    __shared__ __align__(16) float h2t[16 * 256];
    __shared__ float f_lds[8 * 64 * 17];
    __shared__ float scale_lds[64];

    const int tid = threadIdx.x;
    const int wq = __builtin_amdgcn_readfirstlane(tid >> 6);  // wave id 0..7
    const int l = tid & 63;
    const int l4 = l * 4;
    const int item = blockIdx.x * 64 + l;
    const int b = item >> 4;
    const int obase = wq * 8;

    const float t = ts[item];
    const float rTc = __fdividef(0.5f, t);
    const float gamma = 0.001f + 4.6051701859880913680f * rTc;  // -ln(0.01)/Tc

    if (wq == 0) scale_lds[l] = __expf(gamma * t) * rTc;

    // ---- H1: 8 outputs/wave, i-outer, theta/phi on the fly ----
    const float gam2 = gamma * gamma;
    const float rg = __fdividef(1.0f, gamma);
    const float pirTc = PI_F * rTc;

    {
        float acc[8];
        #pragma unroll
        for (int oo = 0; oo < 8; ++oo) acc[oo] = b1[obase + oo];
        const float* w1b = W1 + obase * 85;

        float fk = 0.0f;
        for (int k = 0; k < 33; ++k) {
            float sim = fk * pirTc;
            float vth = atanf(sim * rg);
            float sq = fmaf(sim, sim, gam2);
            float vph = asinf(__fdividef(sq - 1.0f, sq + 1.0f));
            #pragma unroll
            for (int oo = 0; oo < 8; ++oo) {
                acc[oo] = fmaf(vth, w1b[oo * 85 + k], acc[oo]);
                acc[oo] = fmaf(vph, w1b[oo * 85 + 33 + k], acc[oo]);
            }
            fk += 1.0f;
        }
        #pragma unroll
        for (int j = 0; j < 19; ++j) {
            float pv = (j < 17) ? obs[b * 17 + j] : p_act[b * 2 + (j - 17)];
            #pragma unroll
            for (int oo = 0; oo < 8; ++oo)
                acc[oo] = fmaf(pv, w1b[oo * 85 + 66 + j], acc[oo]);
        }
        #pragma unroll
        for (int oo = 0; oo < 8; ++oo) {
            int o = obase + oo;
            h1t[(o >> 2) * 256 + l4 + (o & 3)] = tanh_f(acc[oo]);
        }
    }
    __syncthreads();

    // ---- H2: 8 outputs/wave, h1 read in float4 chunks ----
    {
        float acc[8];
        #pragma unroll
        for (int oo = 0; oo < 8; ++oo) acc[oo] = b2[obase + oo];
        #pragma unroll
        for (int c = 0; c < 16; ++c) {
            const float4 g4 = *reinterpret_cast<const float4*>(&h1t[c * 256 + l4]);
            const float gg[4] = {g4.x, g4.y, g4.z, g4.w};
            #pragma unroll
            for (int oo = 0; oo < 8; ++oo) {
                const float* wr = W2 + (obase + oo) * 64 + c * 4;
                #pragma unroll
                for (int j = 0; j < 4; ++j)
                    acc[oo] = fmaf(gg[j], wr[j], acc[oo]);
            }
        }
        #pragma unroll
        for (int oo = 0; oo < 8; ++oo) {
            int o = obase + oo;
            h2t[(o >> 2) * 256 + l4 + (o & 3)] = tanh_f(acc[oo]);
        }
    }
    __syncthreads();

    // ---- W3 + series epilogue for k ≡ wq (mod 8) ----
    // k%4==0: +cos; 1: -sin; 2: -cos; 3: +sin  (times wk, 0.5 at k=0)
    {
        const float csgn = ((wq & 3) == 1 || (wq & 3) == 2) ? -1.0f : 1.0f;
        float* fout = &f_lds[(wq * 64 + l) * 17];
        if (wq == 0) {
            for (int o = 0; o < 17; ++o)
                fout[o] = w3_o<5, false, true>(W3, b3, h2t, l4, o * 33, 1.0f);
        } else if (wq & 1) {
            for (int o = 0; o < 17; ++o)
                fout[o] = w3_o<4, true, false>(W3, b3, h2t, l4, o * 33 + wq, csgn);
        } else {
            for (int o = 0; o < 17; ++o)
                fout[o] = w3_o<4, false, false>(W3, b3, h2t, l4, o * 33 + wq, csgn);
        }
    }
    __syncthreads();

    // ---- reduce 8 k-class partials, scale, write out ----
    const int base_item = blockIdx.x * 64;
    for (int idx = tid; idx < 64 * 17; idx += 512) {
        const int li = idx / 17;
        const int o  = idx - li * 17;
        float tot = 0.0f;
        #pragma unroll
        for (int q = 0; q < 8; ++q)
            tot += f_lds[(q * 64 + li) * 17 + o];
        out[(base_item + li) * 17 + o] = tot * scale_lds[li];
    }
}

extern "C" void kernel_launch(void* const* d_in, const int* in_sizes, int n_in,
                              void* d_out, int out_size, void* d_ws, size_t ws_size,
                              hipStream_t stream) {
    (void)in_sizes; (void)n_in; (void)out_size; (void)ws_size;
    const float* obs  = (const float*)d_in[0];
    const float* act  = (const float*)d_in[1];
    const float* ts   = (const float*)d_in[2];
    const float* Wih0 = (const float*)d_in[3];
    const float* Whh0 = (const float*)d_in[4];
    const float* bih0 = (const float*)d_in[5];
    const float* bhh0 = (const float*)d_in[6];
    const float* Wih1 = (const float*)d_in[7];
    const float* Whh1 = (const float*)d_in[8];
    const float* bih1 = (const float*)d_in[9];
    const float* bhh1 = (const float*)d_in[10];
    const float* encW = (const float*)d_in[11];
    const float* encb = (const float*)d_in[12];
    const float* W1   = (const float*)d_in[13];
    const float* b1   = (const float*)d_in[14];
    const float* W2   = (const float*)d_in[15];
    const float* b2   = (const float*)d_in[16];
    const float* W3   = (const float*)d_in[17];
    const float* b3   = (const float*)d_in[18];
    float* o_ptr  = (float*)d_out;
    float* p_act  = (float*)d_ws;

    gru_kernel<<<dim3(512), dim3(128), 0, stream>>>(
        act, Wih0, Whh0, bih0, bhh0, Wih1, Whh1, bih1, bhh1, encW, encb, p_act);
    mlp_kernel<<<dim3(512), dim3(512), 0, stream>>>(
        obs, ts, p_act, W1, b1, W2, b2, W3, b3, o_ptr);
}

// Round 7
// 203.147 us; speedup vs baseline: 1.2143x; 1.0884x over previous
//
#include <hip/hip_runtime.h>
#include <math.h>

#define PI_F 3.14159265358979323846f
#define PI_2F 1.57079632679489662f

// ---------------- fast device math ----------------
__device__ __forceinline__ float sigm_f(float x) {
    return __fdividef(1.0f, 1.0f + __expf(-x));
}
__device__ __forceinline__ float tanh_f(float x) {
    float xc = fminf(fmaxf(x, -9.0f), 9.0f);
    float e = __expf(2.0f * xc);
    return 1.0f - __fdividef(2.0f, e + 1.0f);
}
// atan(z) for z in [0,1], max err ~1e-5 rad
__device__ __forceinline__ float atan01(float z) {
    float z2 = z * z;
    float p = fmaf(z2, -0.0117212f, 0.05265332f);
    p = fmaf(z2, p, -0.11643287f);
    p = fmaf(z2, p, 0.19354346f);
    p = fmaf(z2, p, -0.33262347f);
    p = fmaf(z2, p, 0.99997726f);
    return z * p;
}
// atan(x) for x >= 0
__device__ __forceinline__ float atan_pos(float x) {
    bool big = x > 1.0f;
    float z = big ? __fdividef(1.0f, x) : x;
    float p = atan01(z);
    return big ? (PI_2F - p) : p;
}

// ============================================================
// Kernel 1: 2-layer GRU over reversed action sequence + encoder head.
// 128 threads = 4 samples x 32 hidden-lanes. Weights in LDS with
// stride-4 gate-interleave: w[i][j*4 + gate] -> one ds_read_b128 per
// (i, matrix); h broadcast read as float4.
// ============================================================
__global__ __launch_bounds__(128)
void gru_kernel(const float* __restrict__ act,
                const float* __restrict__ Wih0, const float* __restrict__ Whh0,
                const float* __restrict__ bih0, const float* __restrict__ bhh0,
                const float* __restrict__ Wih1, const float* __restrict__ Whh1,
                const float* __restrict__ bih1, const float* __restrict__ bhh1,
                const float* __restrict__ encW, const float* __restrict__ encb,
                float* __restrict__ p_out)
{
    __shared__ __align__(16) float wih0_l[6 * 128];
    __shared__ __align__(16) float whh0_l[32 * 128];
    __shared__ __align__(16) float wih1_l[32 * 128];
    __shared__ __align__(16) float whh1_l[32 * 128];
    __shared__ float enc_l[64];
    __shared__ __align__(16) float xbuf[4 * 32 * 6];
    __shared__ __align__(16) float hbuf0[4][32];
    __shared__ __align__(16) float hbuf1[4][32];

    const int tid = threadIdx.x;

    for (int idx = tid; idx < 96 * 6; idx += 128) {
        int r = idx / 6, c = idx - r * 6;
        wih0_l[c * 128 + (r & 31) * 4 + (r >> 5)] = Wih0[idx];
    }
    for (int idx = tid; idx < 96 * 32; idx += 128) {
        int r = idx >> 5, c = idx & 31;
        int d = c * 128 + (r & 31) * 4 + (r >> 5);
        whh0_l[d] = Whh0[idx];
        wih1_l[d] = Wih1[idx];
        whh1_l[d] = Whh1[idx];
    }
    if (tid < 64) {
        int o = tid >> 5, j = tid & 31;
        enc_l[j * 2 + o] = encW[o * 32 + j];
    }
    {
        const float inv3 = (1.0f / 3.0f);
        int base = blockIdx.x * (4 * 32 * 6);
        for (int idx = tid; idx < 4 * 32 * 6; idx += 128)
            xbuf[idx] = act[base + idx] * inv3;
    }
    __syncthreads();

    const int s = tid >> 5;
    const int j = tid & 31;
    const int b = blockIdx.x * 4 + s;
    const int j4 = j * 4;

    const float bi0r = bih0[j], bi0z = bih0[32 + j], bi0n = bih0[64 + j];
    const float bh0r = bhh0[j], bh0z = bhh0[32 + j], bh0n = bhh0[64 + j];
    const float bi1r = bih1[j], bi1z = bih1[32 + j], bi1n = bih1[64 + j];
    const float bh1r = bhh1[j], bh1z = bhh1[32 + j], bh1n = bhh1[64 + j];

    float* hb0 = &hbuf0[s][0];
    float* hb1 = &hbuf1[s][0];
    hb0[j] = 0.0f;
    hb1[j] = 0.0f;
    float h0 = 0.0f, h1 = 0.0f;
    const float* xs = &xbuf[s * 192];

    for (int t = 0; t < 32; ++t) {
        const float* xt = &xs[(31 - t) * 6];

        // ---- layer 0: input part ----
        float ar = bi0r, az = bi0z, an = bi0n;
        #pragma unroll
        for (int d = 0; d < 6; ++d) {
            float xv = xt[d];
            const float4 w = *reinterpret_cast<const float4*>(&wih0_l[d * 128 + j4]);
            ar = fmaf(xv, w.x, ar); az = fmaf(xv, w.y, az); an = fmaf(xv, w.z, an);
        }
        // ---- layer 0: recurrent part (2 chains, float4 h + w) ----
        {
            float gr[2] = {bh0r, 0.0f}, gz[2] = {bh0z, 0.0f}, gn[2] = {bh0n, 0.0f};
            #pragma unroll
            for (int ib = 0; ib < 32; ib += 4) {
                const int cc = (ib >> 2) & 1;
                const float4 h4 = *reinterpret_cast<const float4*>(&hb0[ib]);
                const float4 w0 = *reinterpret_cast<const float4*>(&whh0_l[(ib + 0) * 128 + j4]);
                const float4 w1 = *reinterpret_cast<const float4*>(&whh0_l[(ib + 1) * 128 + j4]);
                const float4 w2 = *reinterpret_cast<const float4*>(&whh0_l[(ib + 2) * 128 + j4]);
                const float4 w3 = *reinterpret_cast<const float4*>(&whh0_l[(ib + 3) * 128 + j4]);
                gr[cc] = fmaf(h4.x, w0.x, gr[cc]); gz[cc] = fmaf(h4.x, w0.y, gz[cc]); gn[cc] = fmaf(h4.x, w0.z, gn[cc]);
                gr[cc] = fmaf(h4.y, w1.x, gr[cc]); gz[cc] = fmaf(h4.y, w1.y, gz[cc]); gn[cc] = fmaf(h4.y, w1.z, gn[cc]);
                gr[cc] = fmaf(h4.z, w2.x, gr[cc]); gz[cc] = fmaf(h4.z, w2.y, gz[cc]); gn[cc] = fmaf(h4.z, w2.z, gn[cc]);
                gr[cc] = fmaf(h4.w, w3.x, gr[cc]); gz[cc] = fmaf(h4.w, w3.y, gz[cc]); gn[cc] = fmaf(h4.w, w3.z, gn[cc]);
            }
            float r = sigm_f(ar + gr[0] + gr[1]);
            float z = sigm_f(az + gz[0] + gz[1]);
            float n = tanh_f(an + r * (gn[0] + gn[1]));
            h0 = (1.0f - z) * n + z * h0;
            hb0[j] = h0;
        }

        // ---- layer 1: merged input(h0-new) + recurrent(h1-old) ----
        {
            float ai[2][3] = {{bi1r, bi1z, bi1n}, {0.0f, 0.0f, 0.0f}};
            float gi[2][3] = {{bh1r, bh1z, bh1n}, {0.0f, 0.0f, 0.0f}};
            #pragma unroll
            for (int ib = 0; ib < 32; ib += 4) {
                const int cc = (ib >> 2) & 1;
                const float4 h4a = *reinterpret_cast<const float4*>(&hb0[ib]);
                const float4 h4g = *reinterpret_cast<const float4*>(&hb1[ib]);
                #pragma unroll
                for (int u = 0; u < 4; ++u) {
                    const float ha = (u == 0) ? h4a.x : (u == 1) ? h4a.y : (u == 2) ? h4a.z : h4a.w;
                    const float hg = (u == 0) ? h4g.x : (u == 1) ? h4g.y : (u == 2) ? h4g.z : h4g.w;
                    const float4 wa = *reinterpret_cast<const float4*>(&wih1_l[(ib + u) * 128 + j4]);
                    const float4 wg = *reinterpret_cast<const float4*>(&whh1_l[(ib + u) * 128 + j4]);
                    ai[cc][0] = fmaf(ha, wa.x, ai[cc][0]);
                    ai[cc][1] = fmaf(ha, wa.y, ai[cc][1]);
                    ai[cc][2] = fmaf(ha, wa.z, ai[cc][2]);
                    gi[cc][0] = fmaf(hg, wg.x, gi[cc][0]);
                    gi[cc][1] = fmaf(hg, wg.y, gi[cc][1]);
                    gi[cc][2] = fmaf(hg, wg.z, gi[cc][2]);
                }
            }
            float r1 = sigm_f(ai[0][0] + ai[1][0] + gi[0][0] + gi[1][0]);
            float z1 = sigm_f(ai[0][1] + ai[1][1] + gi[0][1] + gi[1][1]);
            float n1 = tanh_f(ai[0][2] + ai[1][2] + r1 * (gi[0][2] + gi[1][2]));
            h1 = (1.0f - z1) * n1 + z1 * h1;
            hb1[j] = h1;
        }
    }

    float v0 = h1 * enc_l[j * 2 + 0];
    float v1 = h1 * enc_l[j * 2 + 1];
    #pragma unroll
    for (int off = 16; off > 0; off >>= 1) {
        v0 += __shfl_xor(v0, off, 32);
        v1 += __shfl_xor(v1, off, 32);
    }
    if (j == 0) {
        p_out[b * 2 + 0] = v0 + encb[0];
        p_out[b * 2 + 1] = v1 + encb[1];
    }
}

// ============================================================
// Kernel 2: per-(b,t) MLP + Laplace series.
// 512 threads = 8 waves; lane = item. Wave wq: H1/H2 outputs
// [wq*8, wq*8+8); W3 k ≡ wq (mod 8), wave 0 adds k=32.
// W3 processes o-PAIRS per h2 sweep (half the ds_reads, 2 weight
// streams). H1 transcendentals via atan poly + asin->atan identity.
// ============================================================

__device__ __forceinline__ float series_tail(float a, float p, float sgnwk, bool use_sin) {
    float theta = tanh_f(a) * PI_F;
    float phi   = tanh_f(p) * (0.5f * PI_F);
    float sph = __sinf(phi), cph = __cosf(phi);
    float rd = __fdividef(1.0f, 1.0f - sph);
    float tr = use_sin ? __sinf(theta) : __cosf(theta);
    return sgnwk * tr * cph * rd;
}

// Two o-rows per h2 sweep. Rows: rb + 8*kk (theta), +561*64 floats (phi).
template<int NP, bool USE_SIN, bool K0HALF>
__device__ __forceinline__ void w3_pair(const float* __restrict__ W3,
                                        const float* __restrict__ b3,
                                        const float* __restrict__ h2t,
                                        const int l4, const int rb0, const int rb1,
                                        const float csgn, float* __restrict__ f0,
                                        float* __restrict__ f1)
{
    float at0[NP], ap0[NP], at1[NP], ap1[NP];
    #pragma unroll
    for (int kk = 0; kk < NP; ++kk) { at0[kk] = 0.0f; ap0[kk] = 0.0f; at1[kk] = 0.0f; ap1[kk] = 0.0f; }
    #pragma unroll
    for (int c = 0; c < 16; ++c) {
        const float4 g4 = *reinterpret_cast<const float4*>(&h2t[c * 256 + l4]);
        #pragma unroll
        for (int kk = 0; kk < NP; ++kk) {
            const float* wt0 = W3 + (rb0 + 8 * kk) * 64 + c * 4;
            const float* wp0 = wt0 + 561 * 64;
            const float* wt1 = W3 + (rb1 + 8 * kk) * 64 + c * 4;
            const float* wp1 = wt1 + 561 * 64;
            at0[kk] = fmaf(g4.x, wt0[0], at0[kk]); at0[kk] = fmaf(g4.y, wt0[1], at0[kk]);
            at0[kk] = fmaf(g4.z, wt0[2], at0[kk]); at0[kk] = fmaf(g4.w, wt0[3], at0[kk]);
            ap0[kk] = fmaf(g4.x, wp0[0], ap0[kk]); ap0[kk] = fmaf(g4.y, wp0[1], ap0[kk]);
            ap0[kk] = fmaf(g4.z, wp0[2], ap0[kk]); ap0[kk] = fmaf(g4.w, wp0[3], ap0[kk]);
            at1[kk] = fmaf(g4.x, wt1[0], at1[kk]); at1[kk] = fmaf(g4.y, wt1[1], at1[kk]);
            at1[kk] = fmaf(g4.z, wt1[2], at1[kk]); at1[kk] = fmaf(g4.w, wt1[3], at1[kk]);
            ap1[kk] = fmaf(g4.x, wp1[0], ap1[kk]); ap1[kk] = fmaf(g4.y, wp1[1], ap1[kk]);
            ap1[kk] = fmaf(g4.z, wp1[2], ap1[kk]); ap1[kk] = fmaf(g4.w, wp1[3], ap1[kk]);
        }
    }
    float facc0 = 0.0f, facc1 = 0.0f;
    #pragma unroll
    for (int kk = 0; kk < NP; ++kk) {
        const int rt0 = rb0 + 8 * kk;
        const int rt1 = rb1 + 8 * kk;
        float wk = (K0HALF && kk == 0) ? 0.5f : 1.0f;
        facc0 += series_tail(at0[kk] + b3[rt0], ap0[kk] + b3[rt0 + 561], csgn * wk, USE_SIN);
        facc1 += series_tail(at1[kk] + b3[rt1], ap1[kk] + b3[rt1 + 561], csgn * wk, USE_SIN);
    }
    *f0 = facc0;
    *f1 = facc1;
}

template<int NP, bool USE_SIN, bool K0HALF>
__device__ __forceinline__ float w3_one(const float* __restrict__ W3,
                                        const float* __restrict__ b3,
                                        const float* __restrict__ h2t,
                                        const int l4, const int rb, const float csgn)
{
    float at[NP], ap[NP];
    #pragma unroll
    for (int kk = 0; kk < NP; ++kk) { at[kk] = 0.0f; ap[kk] = 0.0f; }
    #pragma unroll
    for (int c = 0; c < 16; ++c) {
        const float4 g4 = *reinterpret_cast<const float4*>(&h2t[c * 256 + l4]);
        #pragma unroll
        for (int kk = 0; kk < NP; ++kk) {
            const float* wt = W3 + (rb + 8 * kk) * 64 + c * 4;
            const float* wp = wt + 561 * 64;
            at[kk] = fmaf(g4.x, wt[0], at[kk]); at[kk] = fmaf(g4.y, wt[1], at[kk]);
            at[kk] = fmaf(g4.z, wt[2], at[kk]); at[kk] = fmaf(g4.w, wt[3], at[kk]);
            ap[kk] = fmaf(g4.x, wp[0], ap[kk]); ap[kk] = fmaf(g4.y, wp[1], ap[kk]);
            ap[kk] = fmaf(g4.z, wp[2], ap[kk]); ap[kk] = fmaf(g4.w, wp[3], ap[kk]);
        }
    }
    float facc = 0.0f;
    #pragma unroll
    for (int kk = 0; kk < NP; ++kk) {
        const int rt = rb + 8 * kk;
        float wk = (K0HALF && kk == 0) ? 0.5f : 1.0f;
        facc += series_tail(at[kk] + b3[rt], ap[kk] + b3[rt + 561], csgn * wk, USE_SIN);
    }
    return facc;
}

__global__ __launch_bounds__(512, 4)
void mlp_kernel(const float* __restrict__ obs, const float* __restrict__ ts,
                const float* __restrict__ p_act,
                const float* __restrict__ W1, const float* __restrict__ b1,
                const float* __restrict__ W2, const float* __restrict__ b2,
                const float* __restrict__ W3, const float* __restrict__ b3,
                float* __restrict__ out)
{
    __shared__ __align__(16) float h1t[16 * 256];      // [i>>2][l][i&3]
    __shared__ __align__(16) float h2t[16 * 256];
    __shared__ float f_lds[8 * 64 * 17];
    __shared__ float scale_lds[64];

    const int tid = threadIdx.x;
    const int wq = __builtin_amdgcn_readfirstlane(tid >> 6);  // wave id 0..7
    const int l = tid & 63;
    const int l4 = l * 4;
    const int item = blockIdx.x * 64 + l;
    const int b = item >> 4;
    const int obase = wq * 8;

    const float t = ts[item];
    const float rTc = __fdividef(0.5f, t);
    const float gamma = 0.001f + 4.6051701859880913680f * rTc;  // -ln(0.01)/Tc

    if (wq == 0) scale_lds[l] = __expf(gamma * t) * rTc;

    // ---- H1: 8 outputs/wave, i-outer, theta/phi via atan poly ----
    const float gam2 = gamma * gamma;
    const float rg = __fdividef(1.0f, gamma);
    const float pirTc = PI_F * rTc;

    {
        float acc[8];
        #pragma unroll
        for (int oo = 0; oo < 8; ++oo) acc[oo] = b1[obase + oo];
        const float* w1b = W1 + obase * 85;

        #pragma unroll 3
        for (int k = 0; k < 33; ++k) {
            float sim = (float)k * pirTc;
            float vth = atan_pos(sim * rg);           // atan2(s_im, s_re), s_re>0
            float sq = fmaf(sim, sim, gam2);          // |s|^2, |s| >= 2.09
            float vph = fmaf(-2.0f, atan01(rsqrtf(sq)), PI_2F);  // asin((q-1)/(q+1))
            #pragma unroll
            for (int oo = 0; oo < 8; ++oo) {
                acc[oo] = fmaf(vth, w1b[oo * 85 + k], acc[oo]);
                acc[oo] = fmaf(vph, w1b[oo * 85 + 33 + k], acc[oo]);
            }
        }
        #pragma unroll
        for (int j = 0; j < 19; ++j) {
            float pv = (j < 17) ? obs[b * 17 + j] : p_act[b * 2 + (j - 17)];
            #pragma unroll
            for (int oo = 0; oo < 8; ++oo)
                acc[oo] = fmaf(pv, w1b[oo * 85 + 66 + j], acc[oo]);
        }
        #pragma unroll
        for (int oo = 0; oo < 8; ++oo) {
            int o = obase + oo;
            h1t[(o >> 2) * 256 + l4 + (o & 3)] = tanh_f(acc[oo]);
        }
    }
    __syncthreads();

    // ---- H2: 8 outputs/wave ----
    {
        float acc[8];
        #pragma unroll
        for (int oo = 0; oo < 8; ++oo) acc[oo] = b2[obase + oo];
        #pragma unroll
        for (int c = 0; c < 16; ++c) {
            const float4 g4 = *reinterpret_cast<const float4*>(&h1t[c * 256 + l4]);
            #pragma unroll
            for (int oo = 0; oo < 8; ++oo) {
                const float* wr = W2 + (obase + oo) * 64 + c * 4;
                acc[oo] = fmaf(g4.x, wr[0], acc[oo]);
                acc[oo] = fmaf(g4.y, wr[1], acc[oo]);
                acc[oo] = fmaf(g4.z, wr[2], acc[oo]);
                acc[oo] = fmaf(g4.w, wr[3], acc[oo]);
            }
        }
        #pragma unroll
        for (int oo = 0; oo < 8; ++oo) {
            int o = obase + oo;
            h2t[(o >> 2) * 256 + l4 + (o & 3)] = tanh_f(acc[oo]);
        }
    }
    __syncthreads();

    // ---- W3 + series epilogue for k ≡ wq (mod 8), o-pairs ----
    // k%4==0: +cos; 1: -sin; 2: -cos; 3: +sin (times wk, 0.5 at k=0)
    {
        const float csgn = ((wq & 3) == 1 || (wq & 3) == 2) ? -1.0f : 1.0f;
        float* fout = &f_lds[(wq * 64 + l) * 17];
        if (wq == 0) {
            #pragma unroll 1
            for (int op = 0; op < 8; ++op)
                w3_pair<5, false, true>(W3, b3, h2t, l4, (2 * op) * 33, (2 * op + 1) * 33,
                                        1.0f, &fout[2 * op], &fout[2 * op + 1]);
            fout[16] = w3_one<5, false, true>(W3, b3, h2t, l4, 16 * 33, 1.0f);
        } else if (wq & 1) {
            #pragma unroll 1
            for (int op = 0; op < 8; ++op)
                w3_pair<4, true, false>(W3, b3, h2t, l4, (2 * op) * 33 + wq, (2 * op + 1) * 33 + wq,
                                        csgn, &fout[2 * op], &fout[2 * op + 1]);
            fout[16] = w3_one<4, true, false>(W3, b3, h2t, l4, 16 * 33 + wq, csgn);
        } else {
            #pragma unroll 1
            for (int op = 0; op < 8; ++op)
                w3_pair<4, false, false>(W3, b3, h2t, l4, (2 * op) * 33 + wq, (2 * op + 1) * 33 + wq,
                                        csgn, &fout[2 * op], &fout[2 * op + 1]);
            fout[16] = w3_one<4, false, false>(W3, b3, h2t, l4, 16 * 33 + wq, csgn);
        }
    }
    __syncthreads();

    // ---- reduce 8 k-class partials, scale, write out ----
    const int base_item = blockIdx.x * 64;
    for (int idx = tid; idx < 64 * 17; idx += 512) {
        const int li = idx / 17;
        const int o  = idx - li * 17;
        float tot = 0.0f;
        #pragma unroll
        for (int q = 0; q < 8; ++q)
            tot += f_lds[(q * 64 + li) * 17 + o];
        out[(base_item + li) * 17 + o] = tot * scale_lds[li];
    }
}

extern "C" void kernel_launch(void* const* d_in, const int* in_sizes, int n_in,
                              void* d_out, int out_size, void* d_ws, size_t ws_size,
                              hipStream_t stream) {
    (void)in_sizes; (void)n_in; (void)out_size; (void)ws_size;
    const float* obs  = (const float*)d_in[0];
    const float* act  = (const float*)d_in[1];
    const float* ts   = (const float*)d_in[2];
    const float* Wih0 = (const float*)d_in[3];
    const float* Whh0 = (const float*)d_in[4];
    const float* bih0 = (const float*)d_in[5];
    const float* bhh0 = (const float*)d_in[6];
    const float* Wih1 = (const float*)d_in[7];
    const float* Whh1 = (const float*)d_in[8];
    const float* bih1 = (const float*)d_in[9];
    const float* bhh1 = (const float*)d_in[10];
    const float* encW = (const float*)d_in[11];
    const float* encb = (const float*)d_in[12];
    const float* W1   = (const float*)d_in[13];
    const float* b1   = (const float*)d_in[14];
    const float* W2   = (const float*)d_in[15];
    const float* b2   = (const float*)d_in[16];
    const float* W3   = (const float*)d_in[17];
    const float* b3   = (const float*)d_in[18];
    float* o_ptr  = (float*)d_out;
    float* p_act  = (float*)d_ws;

    gru_kernel<<<dim3(512), dim3(128), 0, stream>>>(
        act, Wih0, Whh0, bih0, bhh0, Wih1, Whh1, bih1, bhh1, encW, encb, p_act);
    mlp_kernel<<<dim3(512), dim3(512), 0, stream>>>(
        obs, ts, p_act, W1, b1, W2, b2, W3, b3, o_ptr);
}

// Round 8
// 198.218 us; speedup vs baseline: 1.2445x; 1.0249x over previous
//
#include <hip/hip_runtime.h>
#include <math.h>

#define PI_F 3.14159265358979323846f
#define PI_2F 1.57079632679489662f

typedef __attribute__((ext_vector_type(8))) short short8;
typedef __attribute__((ext_vector_type(4))) float f32x4;
#define MFMA16(A,B,C) __builtin_amdgcn_mfma_f32_16x16x32_bf16(A,B,C,0,0,0)

// ---------------- fast device math ----------------
__device__ __forceinline__ float sigm_f(float x) {
    return __fdividef(1.0f, 1.0f + __expf(-x));
}
__device__ __forceinline__ float tanh_f(float x) {
    float xc = fminf(fmaxf(x, -9.0f), 9.0f);
    float e = __expf(2.0f * xc);
    return 1.0f - __fdividef(2.0f, e + 1.0f);
}
// atan(z) for z in [0,1], max err ~1e-5 rad
__device__ __forceinline__ float atan01(float z) {
    float z2 = z * z;
    float p = fmaf(z2, -0.0117212f, 0.05265332f);
    p = fmaf(z2, p, -0.11643287f);
    p = fmaf(z2, p, 0.19354346f);
    p = fmaf(z2, p, -0.33262347f);
    p = fmaf(z2, p, 0.99997726f);
    return z * p;
}
__device__ __forceinline__ float atan_pos(float x) {
    bool big = x > 1.0f;
    float z = big ? __fdividef(1.0f, x) : x;
    float p = atan01(z);
    return big ? (PI_2F - p) : p;
}
// f32 -> bf16 (RNE) and back
__device__ __forceinline__ unsigned short f2bf(float x) {
    unsigned int u = __float_as_uint(x);
    return (unsigned short)((u + 0x7FFFu + ((u >> 16) & 1u)) >> 16);
}
__device__ __forceinline__ float bf2f(unsigned short h) {
    return __uint_as_float(((unsigned int)h) << 16);
}

// ============================================================
// Kernel 0: split W3 (1122 x 64 f32) into bf16 hi/lo planes in ws.
// ============================================================
__global__ __launch_bounds__(256)
void w3cvt_kernel(const float* __restrict__ W3,
                  unsigned short* __restrict__ hi,
                  unsigned short* __restrict__ lo)
{
    int i = blockIdx.x * 256 + threadIdx.x;
    if (i < 1122 * 64) {
        float x = W3[i];
        unsigned short h = f2bf(x);
        hi[i] = h;
        lo[i] = f2bf(x - bf2f(h));
    }
}

// ============================================================
// Kernel 1: 2-layer GRU over reversed action sequence + encoder head.
// (unchanged from round 7)
// ============================================================
__global__ __launch_bounds__(128)
void gru_kernel(const float* __restrict__ act,
                const float* __restrict__ Wih0, const float* __restrict__ Whh0,
                const float* __restrict__ bih0, const float* __restrict__ bhh0,
                const float* __restrict__ Wih1, const float* __restrict__ Whh1,
                const float* __restrict__ bih1, const float* __restrict__ bhh1,
                const float* __restrict__ encW, const float* __restrict__ encb,
                float* __restrict__ p_out)
{
    __shared__ __align__(16) float wih0_l[6 * 128];
    __shared__ __align__(16) float whh0_l[32 * 128];
    __shared__ __align__(16) float wih1_l[32 * 128];
    __shared__ __align__(16) float whh1_l[32 * 128];
    __shared__ float enc_l[64];
    __shared__ __align__(16) float xbuf[4 * 32 * 6];
    __shared__ __align__(16) float hbuf0[4][32];
    __shared__ __align__(16) float hbuf1[4][32];

    const int tid = threadIdx.x;

    for (int idx = tid; idx < 96 * 6; idx += 128) {
        int r = idx / 6, c = idx - r * 6;
        wih0_l[c * 128 + (r & 31) * 4 + (r >> 5)] = Wih0[idx];
    }
    for (int idx = tid; idx < 96 * 32; idx += 128) {
        int r = idx >> 5, c = idx & 31;
        int d = c * 128 + (r & 31) * 4 + (r >> 5);
        whh0_l[d] = Whh0[idx];
        wih1_l[d] = Wih1[idx];
        whh1_l[d] = Whh1[idx];
    }
    if (tid < 64) {
        int o = tid >> 5, j = tid & 31;
        enc_l[j * 2 + o] = encW[o * 32 + j];
    }
    {
        const float inv3 = (1.0f / 3.0f);
        int base = blockIdx.x * (4 * 32 * 6);
        for (int idx = tid; idx < 4 * 32 * 6; idx += 128)
            xbuf[idx] = act[base + idx] * inv3;
    }
    __syncthreads();

    const int s = tid >> 5;
    const int j = tid & 31;
    const int b = blockIdx.x * 4 + s;
    const int j4 = j * 4;

    const float bi0r = bih0[j], bi0z = bih0[32 + j], bi0n = bih0[64 + j];
    const float bh0r = bhh0[j], bh0z = bhh0[32 + j], bh0n = bhh0[64 + j];
    const float bi1r = bih1[j], bi1z = bih1[32 + j], bi1n = bih1[64 + j];
    const float bh1r = bhh1[j], bh1z = bhh1[32 + j], bh1n = bhh1[64 + j];

    float* hb0 = &hbuf0[s][0];
    float* hb1 = &hbuf1[s][0];
    hb0[j] = 0.0f;
    hb1[j] = 0.0f;
    float h0 = 0.0f, h1 = 0.0f;
    const float* xs = &xbuf[s * 192];

    for (int t = 0; t < 32; ++t) {
        const float* xt = &xs[(31 - t) * 6];

        float ar = bi0r, az = bi0z, an = bi0n;
        #pragma unroll
        for (int d = 0; d < 6; ++d) {
            float xv = xt[d];
            const float4 w = *reinterpret_cast<const float4*>(&wih0_l[d * 128 + j4]);
            ar = fmaf(xv, w.x, ar); az = fmaf(xv, w.y, az); an = fmaf(xv, w.z, an);
        }
        {
            float gr[2] = {bh0r, 0.0f}, gz[2] = {bh0z, 0.0f}, gn[2] = {bh0n, 0.0f};
            #pragma unroll
            for (int ib = 0; ib < 32; ib += 4) {
                const int cc = (ib >> 2) & 1;
                const float4 h4 = *reinterpret_cast<const float4*>(&hb0[ib]);
                const float4 w0 = *reinterpret_cast<const float4*>(&whh0_l[(ib + 0) * 128 + j4]);
                const float4 w1 = *reinterpret_cast<const float4*>(&whh0_l[(ib + 1) * 128 + j4]);
                const float4 w2 = *reinterpret_cast<const float4*>(&whh0_l[(ib + 2) * 128 + j4]);
                const float4 w3 = *reinterpret_cast<const float4*>(&whh0_l[(ib + 3) * 128 + j4]);
                gr[cc] = fmaf(h4.x, w0.x, gr[cc]); gz[cc] = fmaf(h4.x, w0.y, gz[cc]); gn[cc] = fmaf(h4.x, w0.z, gn[cc]);
                gr[cc] = fmaf(h4.y, w1.x, gr[cc]); gz[cc] = fmaf(h4.y, w1.y, gz[cc]); gn[cc] = fmaf(h4.y, w1.z, gn[cc]);
                gr[cc] = fmaf(h4.z, w2.x, gr[cc]); gz[cc] = fmaf(h4.z, w2.y, gz[cc]); gn[cc] = fmaf(h4.z, w2.z, gn[cc]);
                gr[cc] = fmaf(h4.w, w3.x, gr[cc]); gz[cc] = fmaf(h4.w, w3.y, gz[cc]); gn[cc] = fmaf(h4.w, w3.z, gn[cc]);
            }
            float r = sigm_f(ar + gr[0] + gr[1]);
            float z = sigm_f(az + gz[0] + gz[1]);
            float n = tanh_f(an + r * (gn[0] + gn[1]));
            h0 = (1.0f - z) * n + z * h0;
            hb0[j] = h0;
        }
        {
            float ai[2][3] = {{bi1r, bi1z, bi1n}, {0.0f, 0.0f, 0.0f}};
            float gi[2][3] = {{bh1r, bh1z, bh1n}, {0.0f, 0.0f, 0.0f}};
            #pragma unroll
            for (int ib = 0; ib < 32; ib += 4) {
                const int cc = (ib >> 2) & 1;
                const float4 h4a = *reinterpret_cast<const float4*>(&hb0[ib]);
                const float4 h4g = *reinterpret_cast<const float4*>(&hb1[ib]);
                #pragma unroll
                for (int u = 0; u < 4; ++u) {
                    const float ha = (u == 0) ? h4a.x : (u == 1) ? h4a.y : (u == 2) ? h4a.z : h4a.w;
                    const float hg = (u == 0) ? h4g.x : (u == 1) ? h4g.y : (u == 2) ? h4g.z : h4g.w;
                    const float4 wa = *reinterpret_cast<const float4*>(&wih1_l[(ib + u) * 128 + j4]);
                    const float4 wg = *reinterpret_cast<const float4*>(&whh1_l[(ib + u) * 128 + j4]);
                    ai[cc][0] = fmaf(ha, wa.x, ai[cc][0]);
                    ai[cc][1] = fmaf(ha, wa.y, ai[cc][1]);
                    ai[cc][2] = fmaf(ha, wa.z, ai[cc][2]);
                    gi[cc][0] = fmaf(hg, wg.x, gi[cc][0]);
                    gi[cc][1] = fmaf(hg, wg.y, gi[cc][1]);
                    gi[cc][2] = fmaf(hg, wg.z, gi[cc][2]);
                }
            }
            float r1 = sigm_f(ai[0][0] + ai[1][0] + gi[0][0] + gi[1][0]);
            float z1 = sigm_f(ai[0][1] + ai[1][1] + gi[0][1] + gi[1][1]);
            float n1 = tanh_f(ai[0][2] + ai[1][2] + r1 * (gi[0][2] + gi[1][2]));
            h1 = (1.0f - z1) * n1 + z1 * h1;
            hb1[j] = h1;
        }
    }

    float v0 = h1 * enc_l[j * 2 + 0];
    float v1 = h1 * enc_l[j * 2 + 1];
    #pragma unroll
    for (int off = 16; off > 0; off >>= 1) {
        v0 += __shfl_xor(v0, off, 32);
        v1 += __shfl_xor(v1, off, 32);
    }
    if (j == 0) {
        p_out[b * 2 + 0] = v0 + encb[0];
        p_out[b * 2 + 1] = v1 + encb[1];
    }
}

// ============================================================
// Kernel 2: per-(b,t) MLP + Laplace series.
// 512 threads = 8 waves, 64 items/block. H1/H2: fp32 per-wave
// (8 outputs each) as before. W3 (94% of MACs): split-bf16 MFMA
// 16x16x32, A = W3 rows (from pre-split ws planes), B = h2 items
// (bf16 hi/lo in swizzled LDS). Units = (o, item-group): 17*4 = 68,
// each = 3 row-tiles of 16 (rows k>32 masked w=0). Lane's D regs =
// 4 consecutive W3 rows of one item -> complete series terms in-lane,
// then 2-shuffle k-reduce.
// ============================================================
__global__ __launch_bounds__(512, 4)
void mlp_kernel(const float* __restrict__ obs, const float* __restrict__ ts,
                const float* __restrict__ p_act,
                const float* __restrict__ W1, const float* __restrict__ b1,
                const float* __restrict__ W2, const float* __restrict__ b2,
                const unsigned short* __restrict__ w3hi,
                const unsigned short* __restrict__ w3lo,
                const float* __restrict__ b3,
                float* __restrict__ out)
{
    __shared__ __align__(16) float h1t[16 * 256];          // [i>>2][l][i&3]
    __shared__ __align__(16) unsigned short b_hi[64 * 64]; // [item][k^((item&7)<<3)]
    __shared__ __align__(16) unsigned short b_lo[64 * 64];
    __shared__ float f_lds[17 * 64];                       // [o][item]
    __shared__ float scale_lds[64];

    const int tid = threadIdx.x;
    const int wq = __builtin_amdgcn_readfirstlane(tid >> 6);  // wave id 0..7
    const int l = tid & 63;
    const int l4 = l * 4;
    const int item = blockIdx.x * 64 + l;
    const int b = item >> 4;
    const int obase = wq * 8;

    const float t = ts[item];
    const float rTc = __fdividef(0.5f, t);
    const float gamma = 0.001f + 4.6051701859880913680f * rTc;  // -ln(0.01)/Tc

    if (wq == 0) scale_lds[l] = __expf(gamma * t) * rTc;

    // ---- H1: 8 outputs/wave, i-outer, theta/phi via atan poly ----
    const float gam2 = gamma * gamma;
    const float rg = __fdividef(1.0f, gamma);
    const float pirTc = PI_F * rTc;

    {
        float acc[8];
        #pragma unroll
        for (int oo = 0; oo < 8; ++oo) acc[oo] = b1[obase + oo];
        const float* w1b = W1 + obase * 85;

        #pragma unroll 3
        for (int k = 0; k < 33; ++k) {
            float sim = (float)k * pirTc;
            float vth = atan_pos(sim * rg);
            float sq = fmaf(sim, sim, gam2);
            float vph = fmaf(-2.0f, atan01(rsqrtf(sq)), PI_2F);
            #pragma unroll
            for (int oo = 0; oo < 8; ++oo) {
                acc[oo] = fmaf(vth, w1b[oo * 85 + k], acc[oo]);
                acc[oo] = fmaf(vph, w1b[oo * 85 + 33 + k], acc[oo]);
            }
        }
        #pragma unroll
        for (int j = 0; j < 19; ++j) {
            float pv = (j < 17) ? obs[b * 17 + j] : p_act[b * 2 + (j - 17)];
            #pragma unroll
            for (int oo = 0; oo < 8; ++oo)
                acc[oo] = fmaf(pv, w1b[oo * 85 + 66 + j], acc[oo]);
        }
        #pragma unroll
        for (int oo = 0; oo < 8; ++oo) {
            int o = obase + oo;
            h1t[(o >> 2) * 256 + l4 + (o & 3)] = tanh_f(acc[oo]);
        }
    }
    __syncthreads();

    // ---- H2: 8 outputs/wave; store as bf16 hi/lo B-fragments ----
    {
        float acc[8];
        #pragma unroll
        for (int oo = 0; oo < 8; ++oo) acc[oo] = b2[obase + oo];
        #pragma unroll
        for (int c = 0; c < 16; ++c) {
            const float4 g4 = *reinterpret_cast<const float4*>(&h1t[c * 256 + l4]);
            #pragma unroll
            for (int oo = 0; oo < 8; ++oo) {
                const float* wr = W2 + (obase + oo) * 64 + c * 4;
                acc[oo] = fmaf(g4.x, wr[0], acc[oo]);
                acc[oo] = fmaf(g4.y, wr[1], acc[oo]);
                acc[oo] = fmaf(g4.z, wr[2], acc[oo]);
                acc[oo] = fmaf(g4.w, wr[3], acc[oo]);
            }
        }
        const int sw = (l & 7) << 3;  // XOR swizzle for this item's row
        #pragma unroll
        for (int p = 0; p < 4; ++p) {
            float v0 = tanh_f(acc[2 * p + 0]);
            float v1 = tanh_f(acc[2 * p + 1]);
            unsigned short h0 = f2bf(v0), h1v = f2bf(v1);
            unsigned short q0 = f2bf(v0 - bf2f(h0)), q1 = f2bf(v1 - bf2f(h1v));
            int ksw = (obase + 2 * p) ^ sw;   // pair stays adjacent (bit0 free)
            *reinterpret_cast<unsigned int*>(&b_hi[l * 64 + ksw]) =
                (unsigned int)h0 | ((unsigned int)h1v << 16);
            *reinterpret_cast<unsigned int*>(&b_lo[l * 64 + ksw]) =
                (unsigned int)q0 | ((unsigned int)q1 << 16);
        }
    }
    __syncthreads();

    // ---- W3 via split-bf16 MFMA + series epilogue ----
    {
        const int lm = l & 15;      // A/B fragment row lane
        const int lq = l >> 4;      // k-slice quarter
        const int ksl = lq * 8;     // fragment k base (logical)

        for (int u = wq; u < 68; u += 8) {
            const int o = u >> 2;
            const int g = u & 3;
            const int itm = g * 16 + lm;
            const int sw = (itm & 7) << 3;
            const unsigned short* bbh = &b_hi[itm * 64];
            const unsigned short* bbl = &b_lo[itm * 64];
            const int kx0 = ksl ^ sw;
            const int kx1 = (32 + ksl) ^ sw;
            const short8 Bh0 = *reinterpret_cast<const short8*>(bbh + kx0);
            const short8 Bh1 = *reinterpret_cast<const short8*>(bbh + kx1);
            const short8 Bl0 = *reinterpret_cast<const short8*>(bbl + kx0);
            const short8 Bl1 = *reinterpret_cast<const short8*>(bbl + kx1);

            float fsum = 0.0f;
            #pragma unroll
            for (int mt = 0; mt < 3; ++mt) {
                const int n0 = o * 33 + mt * 16;
                const int rt = n0 + lm;                       // theta A-row (<=575, in-bounds)
                const int rp = min(n0 + 561 + lm, 1121);      // phi A-row, clamped
                const unsigned short* wt = w3hi + rt * 64 + ksl;
                const unsigned short* wtl = w3lo + rt * 64 + ksl;
                const unsigned short* wp = w3hi + rp * 64 + ksl;
                const unsigned short* wpl = w3lo + rp * 64 + ksl;
                const short8 Ath0 = *reinterpret_cast<const short8*>(wt);
                const short8 Ath1 = *reinterpret_cast<const short8*>(wt + 32);
                const short8 Atl0 = *reinterpret_cast<const short8*>(wtl);
                const short8 Atl1 = *reinterpret_cast<const short8*>(wtl + 32);
                const short8 Aph0 = *reinterpret_cast<const short8*>(wp);
                const short8 Aph1 = *reinterpret_cast<const short8*>(wp + 32);
                const short8 Apl0 = *reinterpret_cast<const short8*>(wpl);
                const short8 Apl1 = *reinterpret_cast<const short8*>(wpl + 32);

                f32x4 aT = {0.0f, 0.0f, 0.0f, 0.0f};
                f32x4 aP = {0.0f, 0.0f, 0.0f, 0.0f};
                aT = MFMA16(Ath0, Bh0, aT); aP = MFMA16(Aph0, Bh0, aP);
                aT = MFMA16(Ath1, Bh1, aT); aP = MFMA16(Aph1, Bh1, aP);
                aT = MFMA16(Ath0, Bl0, aT); aP = MFMA16(Aph0, Bl0, aP);
                aT = MFMA16(Ath1, Bl1, aT); aP = MFMA16(Aph1, Bl1, aP);
                aT = MFMA16(Atl0, Bh0, aT); aP = MFMA16(Apl0, Bh0, aP);
                aT = MFMA16(Atl1, Bh1, aT); aP = MFMA16(Apl1, Bh1, aP);

                const int rd = n0 + lq * 4;   // D-row base for this lane
                #pragma unroll
                for (int reg = 0; reg < 4; ++reg) {
                    const int r = rd + reg;
                    const int k = r - o * 33;
                    const float bt = b3[r];                      // theta bias (in-bounds)
                    const float bp = b3[min(r + 561, 1121)];     // phi bias, clamped
                    float at = aT[reg] + bt;
                    float ap = aP[reg] + bp;
                    float th = tanh_f(at) * PI_F;
                    float ph = tanh_f(ap) * (0.5f * PI_F);
                    float sph = __sinf(ph), cph = __cosf(ph);
                    float rdv = __fdividef(1.0f, 1.0f - sph);
                    float trc = __cosf(th), trs = __sinf(th);
                    float tr = (k & 1) ? trs : trc;
                    float w = (k == 0) ? 0.5f : 1.0f;
                    w = ((k + 1) & 2) ? -w : w;
                    w = (k > 32) ? 0.0f : w;
                    fsum = fmaf(w, tr * cph * rdv, fsum);
                }
            }
            fsum += __shfl_xor(fsum, 16);
            fsum += __shfl_xor(fsum, 32);
            if (l < 16) f_lds[o * 64 + g * 16 + l] = fsum;
        }
    }
    __syncthreads();

    // ---- scale + write out ----
    const int base_item = blockIdx.x * 64;
    for (int idx = tid; idx < 64 * 17; idx += 512) {
        const int li = idx / 17;
        const int o  = idx - li * 17;
        out[(base_item + li) * 17 + o] = f_lds[o * 64 + li] * scale_lds[li];
    }
}

extern "C" void kernel_launch(void* const* d_in, const int* in_sizes, int n_in,
                              void* d_out, int out_size, void* d_ws, size_t ws_size,
                              hipStream_t stream) {
    (void)in_sizes; (void)n_in; (void)out_size; (void)ws_size;
    const float* obs  = (const float*)d_in[0];
    const float* act  = (const float*)d_in[1];
    const float* ts   = (const float*)d_in[2];
    const float* Wih0 = (const float*)d_in[3];
    const float* Whh0 = (const float*)d_in[4];
    const float* bih0 = (const float*)d_in[5];
    const float* bhh0 = (const float*)d_in[6];
    const float* Wih1 = (const float*)d_in[7];
    const float* Whh1 = (const float*)d_in[8];
    const float* bih1 = (const float*)d_in[9];
    const float* bhh1 = (const float*)d_in[10];
    const float* encW = (const float*)d_in[11];
    const float* encb = (const float*)d_in[12];
    const float* W1   = (const float*)d_in[13];
    const float* b1   = (const float*)d_in[14];
    const float* W2   = (const float*)d_in[15];
    const float* b2   = (const float*)d_in[16];
    const float* W3   = (const float*)d_in[17];
    const float* b3   = (const float*)d_in[18];
    float* o_ptr  = (float*)d_out;

    // ws layout: p_act (16KB) | w3hi (1122*64 u16) | w3lo (1122*64 u16)
    float* p_act = (float*)d_ws;
    unsigned short* w3hi = (unsigned short*)((char*)d_ws + 16384);
    unsigned short* w3lo = w3hi + 1122 * 64;

    w3cvt_kernel<<<dim3((1122 * 64 + 255) / 256), dim3(256), 0, stream>>>(W3, w3hi, w3lo);
    gru_kernel<<<dim3(512), dim3(128), 0, stream>>>(
        act, Wih0, Whh0, bih0, bhh0, Wih1, Whh1, bih1, bhh1, encW, encb, p_act);
    mlp_kernel<<<dim3(512), dim3(512), 0, stream>>>(
        obs, ts, p_act, W1, b1, W2, b2, w3hi, w3lo, b3, o_ptr);
}

// Round 9
// 170.839 us; speedup vs baseline: 1.4440x; 1.1603x over previous
//
#include <hip/hip_runtime.h>
#include <math.h>

#define PI_F 3.14159265358979323846f
#define PI_2F 1.57079632679489662f

typedef __attribute__((ext_vector_type(8))) short short8;
typedef __attribute__((ext_vector_type(4))) float f32x4;
#define MFMA16(A,B,C) __builtin_amdgcn_mfma_f32_16x16x32_bf16(A,B,C,0,0,0)

// ---------------- fast device math ----------------
__device__ __forceinline__ float sigm_f(float x) {
    return __fdividef(1.0f, 1.0f + __expf(-x));
}
__device__ __forceinline__ float tanh_f(float x) {
    float xc = fminf(fmaxf(x, -9.0f), 9.0f);
    float e = __expf(2.0f * xc);
    return 1.0f - __fdividef(2.0f, e + 1.0f);
}
// atan(z) for z in [0,1], max err ~1e-5 rad
__device__ __forceinline__ float atan01(float z) {
    float z2 = z * z;
    float p = fmaf(z2, -0.0117212f, 0.05265332f);
    p = fmaf(z2, p, -0.11643287f);
    p = fmaf(z2, p, 0.19354346f);
    p = fmaf(z2, p, -0.33262347f);
    p = fmaf(z2, p, 0.99997726f);
    return z * p;
}
__device__ __forceinline__ float atan_pos(float x) {
    bool big = x > 1.0f;
    float z = big ? __fdividef(1.0f, x) : x;
    float p = atan01(z);
    return big ? (PI_2F - p) : p;
}
// f32 -> bf16 (RNE) and back
__device__ __forceinline__ unsigned short f2bf(float x) {
    unsigned int u = __float_as_uint(x);
    return (unsigned short)((u + 0x7FFFu + ((u >> 16) & 1u)) >> 16);
}
__device__ __forceinline__ float bf2f(unsigned short h) {
    return __uint_as_float(((unsigned int)h) << 16);
}
// unpack a dword holding two bf16 (lo = even input, hi = odd input)
__device__ __forceinline__ float lo16f(unsigned int u) { return __uint_as_float(u << 16); }
__device__ __forceinline__ float hi16f(unsigned int u) { return __uint_as_float(u & 0xFFFF0000u); }

// ============================================================
// Kernel 0: split W3 (1122 x 64 f32) into bf16 hi/lo planes in ws.
// ============================================================
__global__ __launch_bounds__(256)
void w3cvt_kernel(const float* __restrict__ W3,
                  unsigned short* __restrict__ hi,
                  unsigned short* __restrict__ lo)
{
    int i = blockIdx.x * 256 + threadIdx.x;
    if (i < 1122 * 64) {
        float x = W3[i];
        unsigned short h = f2bf(x);
        hi[i] = h;
        lo[i] = f2bf(x - bf2f(h));
    }
}

// ============================================================
// Kernel 1: 2-layer GRU over reversed action sequence + encoder head.
// 128 threads = 4 samples x 32 hidden-lanes. Recurrent/input weight
// matrices staged to LDS as bf16 packed 2-input-rows per 16B:
// [(i/2)*32 + j] * 8 shorts = {r_i0,r_i1, z_i0,z_i1, n_i0,n_i1, pad,pad}
// -> halves LDS broadcast-read traffic (the measured bottleneck).
// ============================================================
__global__ __launch_bounds__(128)
void gru_kernel(const float* __restrict__ act,
                const float* __restrict__ Wih0, const float* __restrict__ Whh0,
                const float* __restrict__ bih0, const float* __restrict__ bhh0,
                const float* __restrict__ Wih1, const float* __restrict__ Whh1,
                const float* __restrict__ bih1, const float* __restrict__ bhh1,
                const float* __restrict__ encW, const float* __restrict__ encb,
                float* __restrict__ p_out)
{
    __shared__ __align__(16) float wih0_l[6 * 128];
    __shared__ __align__(16) unsigned short whh0_p[16 * 32 * 8];
    __shared__ __align__(16) unsigned short wih1_p[16 * 32 * 8];
    __shared__ __align__(16) unsigned short whh1_p[16 * 32 * 8];
    __shared__ float enc_l[64];
    __shared__ __align__(16) float xbuf[4 * 32 * 6];
    __shared__ __align__(16) float hbuf0[4][32];
    __shared__ __align__(16) float hbuf1[4][32];

    const int tid = threadIdx.x;

    for (int idx = tid; idx < 96 * 6; idx += 128) {
        int r = idx / 6, c = idx - r * 6;
        wih0_l[c * 128 + (r & 31) * 4 + (r >> 5)] = Wih0[idx];
    }
    for (int idx = tid; idx < 96 * 32; idx += 128) {
        int r = idx >> 5, c = idx & 31;     // r = gate*32 + j_out, c = input idx
        int g = r >> 5, j = r & 31;
        int d = ((c >> 1) * 32 + j) * 8 + g * 2 + (c & 1);
        whh0_p[d] = f2bf(Whh0[idx]);
        wih1_p[d] = f2bf(Wih1[idx]);
        whh1_p[d] = f2bf(Whh1[idx]);
    }
    if (tid < 64) {
        int o = tid >> 5, j = tid & 31;
        enc_l[j * 2 + o] = encW[o * 32 + j];
    }
    {
        const float inv3 = (1.0f / 3.0f);
        int base = blockIdx.x * (4 * 32 * 6);
        for (int idx = tid; idx < 4 * 32 * 6; idx += 128)
            xbuf[idx] = act[base + idx] * inv3;
    }
    __syncthreads();

    const int s = tid >> 5;
    const int j = tid & 31;
    const int b = blockIdx.x * 4 + s;
    const int j4 = j * 4;

    const float bi0r = bih0[j], bi0z = bih0[32 + j], bi0n = bih0[64 + j];
    const float bh0r = bhh0[j], bh0z = bhh0[32 + j], bh0n = bhh0[64 + j];
    const float bi1r = bih1[j], bi1z = bih1[32 + j], bi1n = bih1[64 + j];
    const float bh1r = bhh1[j], bh1z = bhh1[32 + j], bh1n = bhh1[64 + j];

    float* hb0 = &hbuf0[s][0];
    float* hb1 = &hbuf1[s][0];
    hb0[j] = 0.0f;
    hb1[j] = 0.0f;
    float h0 = 0.0f, h1 = 0.0f;
    const float* xs = &xbuf[s * 192];

    for (int t = 0; t < 32; ++t) {
        const float* xt = &xs[(31 - t) * 6];

        // ---- layer 0: input part (f32 weights) ----
        float ar = bi0r, az = bi0z, an = bi0n;
        #pragma unroll
        for (int d = 0; d < 6; ++d) {
            float xv = xt[d];
            const float4 w = *reinterpret_cast<const float4*>(&wih0_l[d * 128 + j4]);
            ar = fmaf(xv, w.x, ar); az = fmaf(xv, w.y, az); an = fmaf(xv, w.z, an);
        }
        // ---- layer 0: recurrent part (bf16 packed, 2 chains) ----
        {
            float gr0 = bh0r, gz0 = bh0z, gn0 = bh0n;
            float gr1 = 0.0f, gz1 = 0.0f, gn1 = 0.0f;
            #pragma unroll
            for (int ib = 0; ib < 32; ib += 4) {
                const float4 h4 = *reinterpret_cast<const float4*>(&hb0[ib]);
                const uint4 wA = *reinterpret_cast<const uint4*>(&whh0_p[((ib >> 1) * 32 + j) * 8]);
                const uint4 wB = *reinterpret_cast<const uint4*>(&whh0_p[((ib >> 1) * 32 + j + 32) * 8]);
                gr0 = fmaf(h4.x, lo16f(wA.x), gr0); gr1 = fmaf(h4.y, hi16f(wA.x), gr1);
                gz0 = fmaf(h4.x, lo16f(wA.y), gz0); gz1 = fmaf(h4.y, hi16f(wA.y), gz1);
                gn0 = fmaf(h4.x, lo16f(wA.z), gn0); gn1 = fmaf(h4.y, hi16f(wA.z), gn1);
                gr0 = fmaf(h4.z, lo16f(wB.x), gr0); gr1 = fmaf(h4.w, hi16f(wB.x), gr1);
                gz0 = fmaf(h4.z, lo16f(wB.y), gz0); gz1 = fmaf(h4.w, hi16f(wB.y), gz1);
                gn0 = fmaf(h4.z, lo16f(wB.z), gn0); gn1 = fmaf(h4.w, hi16f(wB.z), gn1);
            }
            float r = sigm_f(ar + gr0 + gr1);
            float z = sigm_f(az + gz0 + gz1);
            float n = tanh_f(an + r * (gn0 + gn1));
            h0 = (1.0f - z) * n + z * h0;
            hb0[j] = h0;
        }

        // ---- layer 1: merged input(h0-new) + recurrent(h1-old) ----
        {
            float a1r0 = bi1r, a1z0 = bi1z, a1n0 = bi1n;
            float a1r1 = 0.0f, a1z1 = 0.0f, a1n1 = 0.0f;
            float g1r0 = bh1r, g1z0 = bh1z, g1n0 = bh1n;
            float g1r1 = 0.0f, g1z1 = 0.0f, g1n1 = 0.0f;
            #pragma unroll
            for (int ib = 0; ib < 32; ib += 4) {
                const float4 ha = *reinterpret_cast<const float4*>(&hb0[ib]);
                const float4 hg = *reinterpret_cast<const float4*>(&hb1[ib]);
                const uint4 aA = *reinterpret_cast<const uint4*>(&wih1_p[((ib >> 1) * 32 + j) * 8]);
                const uint4 aB = *reinterpret_cast<const uint4*>(&wih1_p[((ib >> 1) * 32 + j + 32) * 8]);
                const uint4 gA = *reinterpret_cast<const uint4*>(&whh1_p[((ib >> 1) * 32 + j) * 8]);
                const uint4 gB = *reinterpret_cast<const uint4*>(&whh1_p[((ib >> 1) * 32 + j + 32) * 8]);
                a1r0 = fmaf(ha.x, lo16f(aA.x), a1r0); a1r1 = fmaf(ha.y, hi16f(aA.x), a1r1);
                a1z0 = fmaf(ha.x, lo16f(aA.y), a1z0); a1z1 = fmaf(ha.y, hi16f(aA.y), a1z1);
                a1n0 = fmaf(ha.x, lo16f(aA.z), a1n0); a1n1 = fmaf(ha.y, hi16f(aA.z), a1n1);
                a1r0 = fmaf(ha.z, lo16f(aB.x), a1r0); a1r1 = fmaf(ha.w, hi16f(aB.x), a1r1);
                a1z0 = fmaf(ha.z, lo16f(aB.y), a1z0); a1z1 = fmaf(ha.w, hi16f(aB.y), a1z1);
                a1n0 = fmaf(ha.z, lo16f(aB.z), a1n0); a1n1 = fmaf(ha.w, hi16f(aB.z), a1n1);
                g1r0 = fmaf(hg.x, lo16f(gA.x), g1r0); g1r1 = fmaf(hg.y, hi16f(gA.x), g1r1);
                g1z0 = fmaf(hg.x, lo16f(gA.y), g1z0); g1z1 = fmaf(hg.y, hi16f(gA.y), g1z1);
                g1n0 = fmaf(hg.x, lo16f(gA.z), g1n0); g1n1 = fmaf(hg.y, hi16f(gA.z), g1n1);
                g1r0 = fmaf(hg.z, lo16f(gB.x), g1r0); g1r1 = fmaf(hg.w, hi16f(gB.x), g1r1);
                g1z0 = fmaf(hg.z, lo16f(gB.y), g1z0); g1z1 = fmaf(hg.w, hi16f(gB.y), g1z1);
                g1n0 = fmaf(hg.z, lo16f(gB.z), g1n0); g1n1 = fmaf(hg.w, hi16f(gB.z), g1n1);
            }
            float r1 = sigm_f(a1r0 + a1r1 + g1r0 + g1r1);
            float z1 = sigm_f(a1z0 + a1z1 + g1z0 + g1z1);
            float n1 = tanh_f(a1n0 + a1n1 + r1 * (g1n0 + g1n1));
            h1 = (1.0f - z1) * n1 + z1 * h1;
            hb1[j] = h1;
        }
    }

    float v0 = h1 * enc_l[j * 2 + 0];
    float v1 = h1 * enc_l[j * 2 + 1];
    #pragma unroll
    for (int off = 16; off > 0; off >>= 1) {
        v0 += __shfl_xor(v0, off, 32);
        v1 += __shfl_xor(v1, off, 32);
    }
    if (j == 0) {
        p_out[b * 2 + 0] = v0 + encb[0];
        p_out[b * 2 + 1] = v1 + encb[1];
    }
}

// ============================================================
// Kernel 2: per-(b,t) MLP + Laplace series.
// 512 threads = 8 waves, 64 items/block.
// NEW: theta_s/phi_s trig computed ONCE per block (k split across
// waves) into LDS [33][64][2] (was 8x redundant); epilogue uses a
// single sin per term and the k=32 tile computes only its 1 valid
// term (exec-masked). W3 via split-bf16 MFMA as round 8.
// ============================================================
__global__ __launch_bounds__(512, 4)
void mlp_kernel(const float* __restrict__ obs, const float* __restrict__ ts,
                const float* __restrict__ p_act,
                const float* __restrict__ W1, const float* __restrict__ b1,
                const float* __restrict__ W2, const float* __restrict__ b2,
                const unsigned short* __restrict__ w3hi,
                const unsigned short* __restrict__ w3lo,
                const float* __restrict__ b3,
                float* __restrict__ out)
{
    __shared__ __align__(16) float h1t[16 * 256];          // [i>>2][l][i&3]
    __shared__ __align__(16) unsigned short b_hi[64 * 64]; // [item][k^((item&7)<<3)]
    __shared__ __align__(16) unsigned short b_lo[64 * 64];
    __shared__ __align__(8) float vtp_lds[33 * 128];       // [k][l][{th,ph}]
    __shared__ float f_lds[17 * 64];                       // [o][item]
    __shared__ float scale_lds[64];

    const int tid = threadIdx.x;
    const int wq = __builtin_amdgcn_readfirstlane(tid >> 6);  // wave id 0..7
    const int l = tid & 63;
    const int l4 = l * 4;
    const int item = blockIdx.x * 64 + l;
    const int b = item >> 4;
    const int obase = wq * 8;

    const float t = ts[item];
    const float rTc = __fdividef(0.5f, t);
    const float gamma = 0.001f + 4.6051701859880913680f * rTc;  // -ln(0.01)/Tc

    if (wq == 0) scale_lds[l] = __expf(gamma * t) * rTc;

    const float gam2 = gamma * gamma;
    const float rg = __fdividef(1.0f, gamma);
    const float pirTc = PI_F * rTc;

    // ---- trig table: wave wq computes k = wq, wq+8, ... (once/block) ----
    for (int k = wq; k < 33; k += 8) {
        float sim = (float)k * pirTc;
        float vth = atan_pos(sim * rg);
        float sq = fmaf(sim, sim, gam2);
        float vph = fmaf(-2.0f, atan01(rsqrtf(sq)), PI_2F);
        vtp_lds[k * 128 + (l << 1) + 0] = vth;
        vtp_lds[k * 128 + (l << 1) + 1] = vph;
    }
    __syncthreads();

    // ---- H1: 8 outputs/wave, trig from LDS ----
    {
        float acc[8];
        #pragma unroll
        for (int oo = 0; oo < 8; ++oo) acc[oo] = b1[obase + oo];
        const float* w1b = W1 + obase * 85;

        for (int k = 0; k < 33; ++k) {
            const float2 tp = *reinterpret_cast<const float2*>(&vtp_lds[k * 128 + (l << 1)]);
            #pragma unroll
            for (int oo = 0; oo < 8; ++oo) {
                acc[oo] = fmaf(tp.x, w1b[oo * 85 + k], acc[oo]);
                acc[oo] = fmaf(tp.y, w1b[oo * 85 + 33 + k], acc[oo]);
            }
        }
        #pragma unroll
        for (int j = 0; j < 19; ++j) {
            float pv = (j < 17) ? obs[b * 17 + j] : p_act[b * 2 + (j - 17)];
            #pragma unroll
            for (int oo = 0; oo < 8; ++oo)
                acc[oo] = fmaf(pv, w1b[oo * 85 + 66 + j], acc[oo]);
        }
        #pragma unroll
        for (int oo = 0; oo < 8; ++oo) {
            int o = obase + oo;
            h1t[(o >> 2) * 256 + l4 + (o & 3)] = tanh_f(acc[oo]);
        }
    }
    __syncthreads();

    // ---- H2: 8 outputs/wave; store as bf16 hi/lo B-fragments ----
    {
        float acc[8];
        #pragma unroll
        for (int oo = 0; oo < 8; ++oo) acc[oo] = b2[obase + oo];
        #pragma unroll
        for (int c = 0; c < 16; ++c) {
            const float4 g4 = *reinterpret_cast<const float4*>(&h1t[c * 256 + l4]);
            #pragma unroll
            for (int oo = 0; oo < 8; ++oo) {
                const float* wr = W2 + (obase + oo) * 64 + c * 4;
                acc[oo] = fmaf(g4.x, wr[0], acc[oo]);
                acc[oo] = fmaf(g4.y, wr[1], acc[oo]);
                acc[oo] = fmaf(g4.z, wr[2], acc[oo]);
                acc[oo] = fmaf(g4.w, wr[3], acc[oo]);
            }
        }
        const int sw = (l & 7) << 3;  // XOR swizzle for this item's row
        #pragma unroll
        for (int p = 0; p < 4; ++p) {
            float v0 = tanh_f(acc[2 * p + 0]);
            float v1 = tanh_f(acc[2 * p + 1]);
            unsigned short h0 = f2bf(v0), h1v = f2bf(v1);
            unsigned short q0 = f2bf(v0 - bf2f(h0)), q1 = f2bf(v1 - bf2f(h1v));
            int ksw = (obase + 2 * p) ^ sw;   // pair stays adjacent (bit0 free)
            *reinterpret_cast<unsigned int*>(&b_hi[l * 64 + ksw]) =
                (unsigned int)h0 | ((unsigned int)h1v << 16);
            *reinterpret_cast<unsigned int*>(&b_lo[l * 64 + ksw]) =
                (unsigned int)q0 | ((unsigned int)q1 << 16);
        }
    }
    __syncthreads();

    // ---- W3 via split-bf16 MFMA + series epilogue ----
    {
        const int lm = l & 15;      // A/B fragment row lane
        const int lq = l >> 4;      // k-slice quarter
        const int ksl = lq * 8;     // fragment k base (logical)

        for (int u = wq; u < 68; u += 8) {
            const int o = u >> 2;
            const int g = u & 3;
            const int itm = g * 16 + lm;
            const int sw = (itm & 7) << 3;
            const unsigned short* bbh = &b_hi[itm * 64];
            const unsigned short* bbl = &b_lo[itm * 64];
            const int kx0 = ksl ^ sw;
            const int kx1 = (32 + ksl) ^ sw;
            const short8 Bh0 = *reinterpret_cast<const short8*>(bbh + kx0);
            const short8 Bh1 = *reinterpret_cast<const short8*>(bbh + kx1);
            const short8 Bl0 = *reinterpret_cast<const short8*>(bbl + kx0);
            const short8 Bl1 = *reinterpret_cast<const short8*>(bbl + kx1);

            float fsum = 0.0f;
            // ---- k-tiles 0..15 and 16..31 (all terms valid) ----
            #pragma unroll
            for (int mt = 0; mt < 2; ++mt) {
                const int n0 = o * 33 + mt * 16;
                const int rt = n0 + lm;
                const int rp = n0 + 561 + lm;
                const unsigned short* wt  = w3hi + rt * 64 + ksl;
                const unsigned short* wtl = w3lo + rt * 64 + ksl;
                const unsigned short* wp  = w3hi + rp * 64 + ksl;
                const unsigned short* wpl = w3lo + rp * 64 + ksl;
                const short8 Ath0 = *reinterpret_cast<const short8*>(wt);
                const short8 Ath1 = *reinterpret_cast<const short8*>(wt + 32);
                const short8 Atl0 = *reinterpret_cast<const short8*>(wtl);
                const short8 Atl1 = *reinterpret_cast<const short8*>(wtl + 32);
                const short8 Aph0 = *reinterpret_cast<const short8*>(wp);
                const short8 Aph1 = *reinterpret_cast<const short8*>(wp + 32);
                const short8 Apl0 = *reinterpret_cast<const short8*>(wpl);
                const short8 Apl1 = *reinterpret_cast<const short8*>(wpl + 32);

                f32x4 aT = {0.0f, 0.0f, 0.0f, 0.0f};
                f32x4 aP = {0.0f, 0.0f, 0.0f, 0.0f};
                aT = MFMA16(Ath0, Bh0, aT); aP = MFMA16(Aph0, Bh0, aP);
                aT = MFMA16(Ath1, Bh1, aT); aP = MFMA16(Aph1, Bh1, aP);
                aT = MFMA16(Ath0, Bl0, aT); aP = MFMA16(Aph0, Bl0, aP);
                aT = MFMA16(Ath1, Bl1, aT); aP = MFMA16(Aph1, Bl1, aP);
                aT = MFMA16(Atl0, Bh0, aT); aP = MFMA16(Apl0, Bh0, aP);
                aT = MFMA16(Atl1, Bh1, aT); aP = MFMA16(Apl1, Bh1, aP);

                const int rd = n0 + lq * 4;
                #pragma unroll
                for (int reg = 0; reg < 4; ++reg) {
                    const int r = rd + reg;
                    const int k = mt * 16 + lq * 4 + reg;   // 0..31
                    float at = aT[reg] + b3[r];
                    float ap = aP[reg] + b3[r + 561];
                    float th = tanh_f(at) * PI_F;
                    float ph = tanh_f(ap) * (0.5f * PI_F);
                    float sph = __sinf(ph), cph = __cosf(ph);
                    float rdv = __fdividef(1.0f, 1.0f - sph);
                    float tr = __sinf((k & 1) ? th : th + PI_2F);  // sin / cos
                    float w = (k == 0) ? 0.5f : 1.0f;
                    w = ((k + 1) & 2) ? -w : w;
                    fsum = fmaf(w, tr * cph * rdv, fsum);
                }
            }
            // ---- k = 32 tile: only (lq==0, reg 0) is a valid term ----
            {
                const int n0 = o * 33 + 32;
                const int rt = n0 + lm;                      // may spill into phi rows (masked)
                const int rp = min(n0 + 561 + lm, 1121);
                const unsigned short* wt  = w3hi + rt * 64 + ksl;
                const unsigned short* wtl = w3lo + rt * 64 + ksl;
                const unsigned short* wp  = w3hi + rp * 64 + ksl;
                const unsigned short* wpl = w3lo + rp * 64 + ksl;
                const short8 Ath0 = *reinterpret_cast<const short8*>(wt);
                const short8 Ath1 = *reinterpret_cast<const short8*>(wt + 32);
                const short8 Atl0 = *reinterpret_cast<const short8*>(wtl);
                const short8 Atl1 = *reinterpret_cast<const short8*>(wtl + 32);
                const short8 Aph0 = *reinterpret_cast<const short8*>(wp);
                const short8 Aph1 = *reinterpret_cast<const short8*>(wp + 32);
                const short8 Apl0 = *reinterpret_cast<const short8*>(wpl);
                const short8 Apl1 = *reinterpret_cast<const short8*>(wpl + 32);

                f32x4 aT = {0.0f, 0.0f, 0.0f, 0.0f};
                f32x4 aP = {0.0f, 0.0f, 0.0f, 0.0f};
                aT = MFMA16(Ath0, Bh0, aT); aP = MFMA16(Aph0, Bh0, aP);
                aT = MFMA16(Ath1, Bh1, aT); aP = MFMA16(Aph1, Bh1, aP);
                aT = MFMA16(Ath0, Bl0, aT); aP = MFMA16(Aph0, Bl0, aP);
                aT = MFMA16(Ath1, Bl1, aT); aP = MFMA16(Aph1, Bl1, aP);
                aT = MFMA16(Atl0, Bh0, aT); aP = MFMA16(Apl0, Bh0, aP);
                aT = MFMA16(Atl1, Bh1, aT); aP = MFMA16(Apl1, Bh1, aP);

                if (lq == 0) {   // k = 32: +cos, w = 1
                    float at = aT[0] + b3[n0];
                    float ap = aP[0] + b3[n0 + 561];
                    float th = tanh_f(at) * PI_F;
                    float ph = tanh_f(ap) * (0.5f * PI_F);
                    float sph = __sinf(ph), cph = __cosf(ph);
                    float rdv = __fdividef(1.0f, 1.0f - sph);
                    float tr = __sinf(th + PI_2F);
                    fsum = fmaf(1.0f, tr * cph * rdv, fsum);
                }
            }
            fsum += __shfl_xor(fsum, 16);
            fsum += __shfl_xor(fsum, 32);
            if (l < 16) f_lds[o * 64 + g * 16 + l] = fsum;
        }
    }
    __syncthreads();

    // ---- scale + write out ----
    const int base_item = blockIdx.x * 64;
    for (int idx = tid; idx < 64 * 17; idx += 512) {
        const int li = idx / 17;
        const int o  = idx - li * 17;
        out[(base_item + li) * 17 + o] = f_lds[o * 64 + li] * scale_lds[li];
    }
}

extern "C" void kernel_launch(void* const* d_in, const int* in_sizes, int n_in,
                              void* d_out, int out_size, void* d_ws, size_t ws_size,
                              hipStream_t stream) {
    (void)in_sizes; (void)n_in; (void)out_size; (void)ws_size;
    const float* obs  = (const float*)d_in[0];
    const float* act  = (const float*)d_in[1];
    const float* ts   = (const float*)d_in[2];
    const float* Wih0 = (const float*)d_in[3];
    const float* Whh0 = (const float*)d_in[4];
    const float* bih0 = (const float*)d_in[5];
    const float* bhh0 = (const float*)d_in[6];
    const float* Wih1 = (const float*)d_in[7];
    const float* Whh1 = (const float*)d_in[8];
    const float* bih1 = (const float*)d_in[9];
    const float* bhh1 = (const float*)d_in[10];
    const float* encW = (const float*)d_in[11];
    const float* encb = (const float*)d_in[12];
    const float* W1   = (const float*)d_in[13];
    const float* b1   = (const float*)d_in[14];
    const float* W2   = (const float*)d_in[15];
    const float* b2   = (const float*)d_in[16];
    const float* W3   = (const float*)d_in[17];
    const float* b3   = (const float*)d_in[18];
    float* o_ptr  = (float*)d_out;

    // ws layout: p_act (16KB) | w3hi (1122*64 u16) | w3lo (1122*64 u16)
    float* p_act = (float*)d_ws;
    unsigned short* w3hi = (unsigned short*)((char*)d_ws + 16384);
    unsigned short* w3lo = w3hi + 1122 * 64;

    w3cvt_kernel<<<dim3((1122 * 64 + 255) / 256), dim3(256), 0, stream>>>(W3, w3hi, w3lo);
    gru_kernel<<<dim3(512), dim3(128), 0, stream>>>(
        act, Wih0, Whh0, bih0, bhh0, Wih1, Whh1, bih1, bhh1, encW, encb, p_act);
    mlp_kernel<<<dim3(512), dim3(512), 0, stream>>>(
        obs, ts, p_act, W1, b1, W2, b2, w3hi, w3lo, b3, o_ptr);
}

// Round 10
// 161.465 us; speedup vs baseline: 1.5278x; 1.0581x over previous
//
#include <hip/hip_runtime.h>
#include <math.h>

#define PI_F 3.14159265358979323846f
#define PI_2F 1.57079632679489662f

typedef __attribute__((ext_vector_type(8))) short short8;
typedef __attribute__((ext_vector_type(4))) float f32x4;
#define MFMA16(A,B,C) __builtin_amdgcn_mfma_f32_16x16x32_bf16(A,B,C,0,0,0)

// ---------------- fast device math ----------------
__device__ __forceinline__ float sigm_f(float x) {
    return __fdividef(1.0f, 1.0f + __expf(-x));
}
__device__ __forceinline__ float tanh_f(float x) {
    float xc = fminf(fmaxf(x, -9.0f), 9.0f);
    float e = __expf(2.0f * xc);
    return 1.0f - __fdividef(2.0f, e + 1.0f);
}
// atan(z) for z in [0,1], max err ~1e-5 rad
__device__ __forceinline__ float atan01(float z) {
    float z2 = z * z;
    float p = fmaf(z2, -0.0117212f, 0.05265332f);
    p = fmaf(z2, p, -0.11643287f);
    p = fmaf(z2, p, 0.19354346f);
    p = fmaf(z2, p, -0.33262347f);
    p = fmaf(z2, p, 0.99997726f);
    return z * p;
}
__device__ __forceinline__ float atan_pos(float x) {
    bool big = x > 1.0f;
    float z = big ? __fdividef(1.0f, x) : x;
    float p = atan01(z);
    return big ? (PI_2F - p) : p;
}
// f32 -> bf16 (RNE) and back
__device__ __forceinline__ unsigned short f2bf(float x) {
    unsigned int u = __float_as_uint(x);
    return (unsigned short)((u + 0x7FFFu + ((u >> 16) & 1u)) >> 16);
}
__device__ __forceinline__ float bf2f(unsigned short h) {
    return __uint_as_float(((unsigned int)h) << 16);
}
__device__ __forceinline__ float lo16f(unsigned int u) { return __uint_as_float(u << 16); }
__device__ __forceinline__ float hi16f(unsigned int u) { return __uint_as_float(u & 0xFFFF0000u); }

// one Laplace series term; k = series index (sign/weight pattern period 4)
__device__ __forceinline__ float lap_term(float at, float ap, int k) {
    float th = tanh_f(at) * PI_F;
    float ph = tanh_f(ap) * (0.5f * PI_F);
    float sph = __sinf(ph), cph = __cosf(ph);
    float rdv = __fdividef(1.0f, 1.0f - sph);
    float tr = __sinf((k & 1) ? th : th + PI_2F);  // sin for odd k, cos for even
    float w = (k == 0) ? 0.5f : 1.0f;
    w = ((k + 1) & 2) ? -w : w;
    return w * tr * cph * rdv;
}

// ============================================================
// Kernel 0: split W3 (1122 x 64 f32) into bf16 hi/lo planes in ws.
// ============================================================
__global__ __launch_bounds__(256)
void w3cvt_kernel(const float* __restrict__ W3,
                  unsigned short* __restrict__ hi,
                  unsigned short* __restrict__ lo)
{
    int i = blockIdx.x * 256 + threadIdx.x;
    if (i < 1122 * 64) {
        float x = W3[i];
        unsigned short h = f2bf(x);
        hi[i] = h;
        lo[i] = f2bf(x - bf2f(h));
    }
}

// ============================================================
// Kernel 1: 2-layer GRU (unchanged from round 9).
// ============================================================
__global__ __launch_bounds__(128)
void gru_kernel(const float* __restrict__ act,
                const float* __restrict__ Wih0, const float* __restrict__ Whh0,
                const float* __restrict__ bih0, const float* __restrict__ bhh0,
                const float* __restrict__ Wih1, const float* __restrict__ Whh1,
                const float* __restrict__ bih1, const float* __restrict__ bhh1,
                const float* __restrict__ encW, const float* __restrict__ encb,
                float* __restrict__ p_out)
{
    __shared__ __align__(16) float wih0_l[6 * 128];
    __shared__ __align__(16) unsigned short whh0_p[16 * 32 * 8];
    __shared__ __align__(16) unsigned short wih1_p[16 * 32 * 8];
    __shared__ __align__(16) unsigned short whh1_p[16 * 32 * 8];
    __shared__ float enc_l[64];
    __shared__ __align__(16) float xbuf[4 * 32 * 6];
    __shared__ __align__(16) float hbuf0[4][32];
    __shared__ __align__(16) float hbuf1[4][32];

    const int tid = threadIdx.x;

    for (int idx = tid; idx < 96 * 6; idx += 128) {
        int r = idx / 6, c = idx - r * 6;
        wih0_l[c * 128 + (r & 31) * 4 + (r >> 5)] = Wih0[idx];
    }
    for (int idx = tid; idx < 96 * 32; idx += 128) {
        int r = idx >> 5, c = idx & 31;
        int g = r >> 5, j = r & 31;
        int d = ((c >> 1) * 32 + j) * 8 + g * 2 + (c & 1);
        whh0_p[d] = f2bf(Whh0[idx]);
        wih1_p[d] = f2bf(Wih1[idx]);
        whh1_p[d] = f2bf(Whh1[idx]);
    }
    if (tid < 64) {
        int o = tid >> 5, j = tid & 31;
        enc_l[j * 2 + o] = encW[o * 32 + j];
    }
    {
        const float inv3 = (1.0f / 3.0f);
        int base = blockIdx.x * (4 * 32 * 6);
        for (int idx = tid; idx < 4 * 32 * 6; idx += 128)
            xbuf[idx] = act[base + idx] * inv3;
    }
    __syncthreads();

    const int s = tid >> 5;
    const int j = tid & 31;
    const int b = blockIdx.x * 4 + s;
    const int j4 = j * 4;

    const float bi0r = bih0[j], bi0z = bih0[32 + j], bi0n = bih0[64 + j];
    const float bh0r = bhh0[j], bh0z = bhh0[32 + j], bh0n = bhh0[64 + j];
    const float bi1r = bih1[j], bi1z = bih1[32 + j], bi1n = bih1[64 + j];
    const float bh1r = bhh1[j], bh1z = bhh1[32 + j], bh1n = bhh1[64 + j];

    float* hb0 = &hbuf0[s][0];
    float* hb1 = &hbuf1[s][0];
    hb0[j] = 0.0f;
    hb1[j] = 0.0f;
    float h0 = 0.0f, h1 = 0.0f;
    const float* xs = &xbuf[s * 192];

    for (int t = 0; t < 32; ++t) {
        const float* xt = &xs[(31 - t) * 6];

        float ar = bi0r, az = bi0z, an = bi0n;
        #pragma unroll
        for (int d = 0; d < 6; ++d) {
            float xv = xt[d];
            const float4 w = *reinterpret_cast<const float4*>(&wih0_l[d * 128 + j4]);
            ar = fmaf(xv, w.x, ar); az = fmaf(xv, w.y, az); an = fmaf(xv, w.z, an);
        }
        {
            float gr0 = bh0r, gz0 = bh0z, gn0 = bh0n;
            float gr1 = 0.0f, gz1 = 0.0f, gn1 = 0.0f;
            #pragma unroll
            for (int ib = 0; ib < 32; ib += 4) {
                const float4 h4 = *reinterpret_cast<const float4*>(&hb0[ib]);
                const uint4 wA = *reinterpret_cast<const uint4*>(&whh0_p[((ib >> 1) * 32 + j) * 8]);
                const uint4 wB = *reinterpret_cast<const uint4*>(&whh0_p[((ib >> 1) * 32 + j + 32) * 8]);
                gr0 = fmaf(h4.x, lo16f(wA.x), gr0); gr1 = fmaf(h4.y, hi16f(wA.x), gr1);
                gz0 = fmaf(h4.x, lo16f(wA.y), gz0); gz1 = fmaf(h4.y, hi16f(wA.y), gz1);
                gn0 = fmaf(h4.x, lo16f(wA.z), gn0); gn1 = fmaf(h4.y, hi16f(wA.z), gn1);
                gr0 = fmaf(h4.z, lo16f(wB.x), gr0); gr1 = fmaf(h4.w, hi16f(wB.x), gr1);
                gz0 = fmaf(h4.z, lo16f(wB.y), gz0); gz1 = fmaf(h4.w, hi16f(wB.y), gz1);
                gn0 = fmaf(h4.z, lo16f(wB.z), gn0); gn1 = fmaf(h4.w, hi16f(wB.z), gn1);
            }
            float r = sigm_f(ar + gr0 + gr1);
            float z = sigm_f(az + gz0 + gz1);
            float n = tanh_f(an + r * (gn0 + gn1));
            h0 = (1.0f - z) * n + z * h0;
            hb0[j] = h0;
        }
        {
            float a1r0 = bi1r, a1z0 = bi1z, a1n0 = bi1n;
            float a1r1 = 0.0f, a1z1 = 0.0f, a1n1 = 0.0f;
            float g1r0 = bh1r, g1z0 = bh1z, g1n0 = bh1n;
            float g1r1 = 0.0f, g1z1 = 0.0f, g1n1 = 0.0f;
            #pragma unroll
            for (int ib = 0; ib < 32; ib += 4) {
                const float4 ha = *reinterpret_cast<const float4*>(&hb0[ib]);
                const float4 hg = *reinterpret_cast<const float4*>(&hb1[ib]);
                const uint4 aA = *reinterpret_cast<const uint4*>(&wih1_p[((ib >> 1) * 32 + j) * 8]);
                const uint4 aB = *reinterpret_cast<const uint4*>(&wih1_p[((ib >> 1) * 32 + j + 32) * 8]);
                const uint4 gA = *reinterpret_cast<const uint4*>(&whh1_p[((ib >> 1) * 32 + j) * 8]);
                const uint4 gB = *reinterpret_cast<const uint4*>(&whh1_p[((ib >> 1) * 32 + j + 32) * 8]);
                a1r0 = fmaf(ha.x, lo16f(aA.x), a1r0); a1r1 = fmaf(ha.y, hi16f(aA.x), a1r1);
                a1z0 = fmaf(ha.x, lo16f(aA.y), a1z0); a1z1 = fmaf(ha.y, hi16f(aA.y), a1z1);
                a1n0 = fmaf(ha.x, lo16f(aA.z), a1n0); a1n1 = fmaf(ha.y, hi16f(aA.z), a1n1);
                a1r0 = fmaf(ha.z, lo16f(aB.x), a1r0); a1r1 = fmaf(ha.w, hi16f(aB.x), a1r1);
                a1z0 = fmaf(ha.z, lo16f(aB.y), a1z0); a1z1 = fmaf(ha.w, hi16f(aB.y), a1z1);
                a1n0 = fmaf(ha.z, lo16f(aB.z), a1n0); a1n1 = fmaf(ha.w, hi16f(aB.z), a1n1);
                g1r0 = fmaf(hg.x, lo16f(gA.x), g1r0); g1r1 = fmaf(hg.y, hi16f(gA.x), g1r1);
                g1z0 = fmaf(hg.x, lo16f(gA.y), g1z0); g1z1 = fmaf(hg.y, hi16f(gA.y), g1z1);
                g1n0 = fmaf(hg.x, lo16f(gA.z), g1n0); g1n1 = fmaf(hg.y, hi16f(gA.z), g1n1);
                g1r0 = fmaf(hg.z, lo16f(gB.x), g1r0); g1r1 = fmaf(hg.w, hi16f(gB.x), g1r1);
                g1z0 = fmaf(hg.z, lo16f(gB.y), g1z0); g1z1 = fmaf(hg.w, hi16f(gB.y), g1z1);
                g1n0 = fmaf(hg.z, lo16f(gB.z), g1n0); g1n1 = fmaf(hg.w, hi16f(gB.z), g1n1);
            }
            float r1 = sigm_f(a1r0 + a1r1 + g1r0 + g1r1);
            float z1 = sigm_f(a1z0 + a1z1 + g1z0 + g1z1);
            float n1 = tanh_f(a1n0 + a1n1 + r1 * (g1n0 + g1n1));
            h1 = (1.0f - z1) * n1 + z1 * h1;
            hb1[j] = h1;
        }
    }

    float v0 = h1 * enc_l[j * 2 + 0];
    float v1 = h1 * enc_l[j * 2 + 1];
    #pragma unroll
    for (int off = 16; off > 0; off >>= 1) {
        v0 += __shfl_xor(v0, off, 32);
        v1 += __shfl_xor(v1, off, 32);
    }
    if (j == 0) {
        p_out[b * 2 + 0] = v0 + encb[0];
        p_out[b * 2 + 1] = v1 + encb[1];
    }
}

// ============================================================
// Kernel 2: per-(b,t) MLP + Laplace series.
// W3 restructured: wave wq owns o = {2wq, 2wq+1}; A-fragments
// loaded once per (o,mt) and reused across all 4 item-groups
// (48 MFMA per A-load batch -> L2 latency hidden, 5x less traffic).
// k=32 rows leave MFMA: per-lane fp32 dot (lane=item, s_load
// weights) against fp32 h2 (reuses the dead h1t buffer).
// o=16: waves 0-3 per-g MFMA, wave 4 its k32 -> f16k32.
// ============================================================

struct AF { short8 th0, th1, tl0, tl1, ph0, ph1, pl0, pl1; };

__device__ __forceinline__ AF load_A(const unsigned short* __restrict__ w3hi,
                                     const unsigned short* __restrict__ w3lo,
                                     int n0, int lm, int ksl)
{
    AF A;
    const unsigned short* wt  = w3hi + (n0 + lm) * 64 + ksl;
    const unsigned short* wtl = w3lo + (n0 + lm) * 64 + ksl;
    const unsigned short* wp  = w3hi + (n0 + 561 + lm) * 64 + ksl;
    const unsigned short* wpl = w3lo + (n0 + 561 + lm) * 64 + ksl;
    A.th0 = *reinterpret_cast<const short8*>(wt);
    A.th1 = *reinterpret_cast<const short8*>(wt + 32);
    A.tl0 = *reinterpret_cast<const short8*>(wtl);
    A.tl1 = *reinterpret_cast<const short8*>(wtl + 32);
    A.ph0 = *reinterpret_cast<const short8*>(wp);
    A.ph1 = *reinterpret_cast<const short8*>(wp + 32);
    A.pl0 = *reinterpret_cast<const short8*>(wpl);
    A.pl1 = *reinterpret_cast<const short8*>(wpl + 32);
    return A;
}

__device__ __forceinline__ void load_B(const unsigned short* b_hi, const unsigned short* b_lo,
                                       int itm, int ksl,
                                       short8& Bh0, short8& Bh1, short8& Bl0, short8& Bl1)
{
    const int sw = (itm & 7) << 3;
    const int kx0 = ksl ^ sw;
    const int kx1 = (32 + ksl) ^ sw;
    Bh0 = *reinterpret_cast<const short8*>(&b_hi[itm * 64 + kx0]);
    Bh1 = *reinterpret_cast<const short8*>(&b_hi[itm * 64 + kx1]);
    Bl0 = *reinterpret_cast<const short8*>(&b_lo[itm * 64 + kx0]);
    Bl1 = *reinterpret_cast<const short8*>(&b_lo[itm * 64 + kx1]);
}

__device__ __forceinline__ void mfma12(const AF& A, short8 Bh0, short8 Bh1,
                                       short8 Bl0, short8 Bl1, f32x4& aT, f32x4& aP)
{
    aT = MFMA16(A.th0, Bh0, aT); aP = MFMA16(A.ph0, Bh0, aP);
    aT = MFMA16(A.th1, Bh1, aT); aP = MFMA16(A.ph1, Bh1, aP);
    aT = MFMA16(A.th0, Bl0, aT); aP = MFMA16(A.ph0, Bl0, aP);
    aT = MFMA16(A.th1, Bl1, aT); aP = MFMA16(A.ph1, Bl1, aP);
    aT = MFMA16(A.tl0, Bh0, aT); aP = MFMA16(A.pl0, Bh0, aP);
    aT = MFMA16(A.tl1, Bh1, aT); aP = MFMA16(A.pl1, Bh1, aP);
}

// k=32 series term for one o: per-lane fp32 dot (lane = item).
__device__ __forceinline__ float k32_term(const float* __restrict__ W3f,
                                          const float* __restrict__ b3,
                                          const float* __restrict__ h2f,
                                          int o, int l4)
{
    const int rt = o * 33 + 32;
    const float* wtr = W3f + rt * 64;
    const float* wpr = W3f + (rt + 561) * 64;
    float at = b3[rt], ap = b3[rt + 561];
    #pragma unroll
    for (int c = 0; c < 16; ++c) {
        const float4 g4 = *reinterpret_cast<const float4*>(&h2f[c * 256 + l4]);
        at = fmaf(g4.x, wtr[c * 4 + 0], at);
        at = fmaf(g4.y, wtr[c * 4 + 1], at);
        at = fmaf(g4.z, wtr[c * 4 + 2], at);
        at = fmaf(g4.w, wtr[c * 4 + 3], at);
        ap = fmaf(g4.x, wpr[c * 4 + 0], ap);
        ap = fmaf(g4.y, wpr[c * 4 + 1], ap);
        ap = fmaf(g4.z, wpr[c * 4 + 2], ap);
        ap = fmaf(g4.w, wpr[c * 4 + 3], ap);
    }
    return lap_term(at, ap, 32);
}

__global__ __launch_bounds__(512, 4)
void mlp_kernel(const float* __restrict__ obs, const float* __restrict__ ts,
                const float* __restrict__ p_act,
                const float* __restrict__ W1, const float* __restrict__ b1,
                const float* __restrict__ W2, const float* __restrict__ b2,
                const unsigned short* __restrict__ w3hi,
                const unsigned short* __restrict__ w3lo,
                const float* __restrict__ b3,
                const float* __restrict__ W3f,
                float* __restrict__ out)
{
    __shared__ __align__(16) float h1t[16 * 256];          // h1 chunks; reused as fp32 h2
    __shared__ __align__(16) unsigned short b_hi[64 * 64]; // [item][k^((item&7)<<3)]
    __shared__ __align__(16) unsigned short b_lo[64 * 64];
    __shared__ __align__(8) float vtp_lds[33 * 128];       // [k][l][{th,ph}]
    __shared__ float f_lds[17 * 64];                       // [o][item]
    __shared__ float f16k32[64];                           // o=16 k32 terms
    __shared__ float scale_lds[64];

    const int tid = threadIdx.x;
    const int wq = __builtin_amdgcn_readfirstlane(tid >> 6);  // wave id 0..7
    const int l = tid & 63;
    const int l4 = l * 4;
    const int item = blockIdx.x * 64 + l;
    const int b = item >> 4;
    const int obase = wq * 8;

    const float t = ts[item];
    const float rTc = __fdividef(0.5f, t);
    const float gamma = 0.001f + 4.6051701859880913680f * rTc;  // -ln(0.01)/Tc

    if (wq == 0) scale_lds[l] = __expf(gamma * t) * rTc;

    const float gam2 = gamma * gamma;
    const float rg = __fdividef(1.0f, gamma);
    const float pirTc = PI_F * rTc;

    // ---- trig table (once per block, k split across waves) ----
    for (int k = wq; k < 33; k += 8) {
        float sim = (float)k * pirTc;
        float vth = atan_pos(sim * rg);
        float sq = fmaf(sim, sim, gam2);
        float vph = fmaf(-2.0f, atan01(rsqrtf(sq)), PI_2F);
        vtp_lds[k * 128 + (l << 1) + 0] = vth;
        vtp_lds[k * 128 + (l << 1) + 1] = vph;
    }
    __syncthreads();

    // ---- H1: 8 outputs/wave ----
    {
        float acc[8];
        #pragma unroll
        for (int oo = 0; oo < 8; ++oo) acc[oo] = b1[obase + oo];
        const float* w1b = W1 + obase * 85;

        for (int k = 0; k < 33; ++k) {
            const float2 tp = *reinterpret_cast<const float2*>(&vtp_lds[k * 128 + (l << 1)]);
            #pragma unroll
            for (int oo = 0; oo < 8; ++oo) {
                acc[oo] = fmaf(tp.x, w1b[oo * 85 + k], acc[oo]);
                acc[oo] = fmaf(tp.y, w1b[oo * 85 + 33 + k], acc[oo]);
            }
        }
        #pragma unroll
        for (int j = 0; j < 19; ++j) {
            float pv = (j < 17) ? obs[b * 17 + j] : p_act[b * 2 + (j - 17)];
            #pragma unroll
            for (int oo = 0; oo < 8; ++oo)
                acc[oo] = fmaf(pv, w1b[oo * 85 + 66 + j], acc[oo]);
        }
        #pragma unroll
        for (int oo = 0; oo < 8; ++oo) {
            int o = obase + oo;
            h1t[(o >> 2) * 256 + l4 + (o & 3)] = tanh_f(acc[oo]);
        }
    }
    __syncthreads();

    // ---- H2: 8 outputs/wave; bf16 hi/lo B-fragments + keep fp32 in regs ----
    float th2[8];
    {
        float acc[8];
        #pragma unroll
        for (int oo = 0; oo < 8; ++oo) acc[oo] = b2[obase + oo];
        #pragma unroll
        for (int c = 0; c < 16; ++c) {
            const float4 g4 = *reinterpret_cast<const float4*>(&h1t[c * 256 + l4]);
            #pragma unroll
            for (int oo = 0; oo < 8; ++oo) {
                const float* wr = W2 + (obase + oo) * 64 + c * 4;
                acc[oo] = fmaf(g4.x, wr[0], acc[oo]);
                acc[oo] = fmaf(g4.y, wr[1], acc[oo]);
                acc[oo] = fmaf(g4.z, wr[2], acc[oo]);
                acc[oo] = fmaf(g4.w, wr[3], acc[oo]);
            }
        }
        #pragma unroll
        for (int oo = 0; oo < 8; ++oo) th2[oo] = tanh_f(acc[oo]);

        const int sw = (l & 7) << 3;
        #pragma unroll
        for (int p = 0; p < 4; ++p) {
            float v0 = th2[2 * p + 0];
            float v1 = th2[2 * p + 1];
            unsigned short h0 = f2bf(v0), h1v = f2bf(v1);
            unsigned short q0 = f2bf(v0 - bf2f(h0)), q1 = f2bf(v1 - bf2f(h1v));
            int ksw = (obase + 2 * p) ^ sw;
            *reinterpret_cast<unsigned int*>(&b_hi[l * 64 + ksw]) =
                (unsigned int)h0 | ((unsigned int)h1v << 16);
            *reinterpret_cast<unsigned int*>(&b_lo[l * 64 + ksw]) =
                (unsigned int)q0 | ((unsigned int)q1 << 16);
        }
    }
    __syncthreads();
    // overwrite dead h1t with fp32 h2 (for the k32 VALU path)
    #pragma unroll
    for (int oo = 0; oo < 8; ++oo) {
        int o = obase + oo;
        h1t[(o >> 2) * 256 + l4 + (o & 3)] = th2[oo];
    }
    __syncthreads();

    // ---- W3: MFMA with A-reuse across all 4 item-groups ----
    {
        const int lm = l & 15;
        const int lq = l >> 4;
        const int ksl = lq * 8;

        #pragma unroll 1
        for (int oo2 = 0; oo2 < 2; ++oo2) {
            const int o = wq * 2 + oo2;
            const float k32t = k32_term(W3f, b3, h1t, o, l4);

            float facc0 = 0.0f, facc1 = 0.0f, facc2 = 0.0f, facc3 = 0.0f;
            #pragma unroll 1
            for (int mt = 0; mt < 2; ++mt) {
                const int n0 = o * 33 + mt * 16;
                const AF A = load_A(w3hi, w3lo, n0, lm, ksl);
                const int rd = n0 + lq * 4;
                float bt[4], bp[4];
                #pragma unroll
                for (int r = 0; r < 4; ++r) {
                    bt[r] = b3[rd + r];
                    bp[r] = b3[rd + r + 561];
                }
                #pragma unroll
                for (int g = 0; g < 4; ++g) {
                    short8 Bh0, Bh1, Bl0, Bl1;
                    load_B(b_hi, b_lo, g * 16 + lm, ksl, Bh0, Bh1, Bl0, Bl1);
                    f32x4 aT = {0.0f, 0.0f, 0.0f, 0.0f};
                    f32x4 aP = {0.0f, 0.0f, 0.0f, 0.0f};
                    mfma12(A, Bh0, Bh1, Bl0, Bl1, aT, aP);
                    float ts_ = 0.0f;
                    #pragma unroll
                    for (int r = 0; r < 4; ++r)
                        ts_ += lap_term(aT[r] + bt[r], aP[r] + bp[r], mt * 16 + lq * 4 + r);
                    if (g == 0) facc0 += ts_;
                    else if (g == 1) facc1 += ts_;
                    else if (g == 2) facc2 += ts_;
                    else facc3 += ts_;
                }
            }
            facc0 += __shfl_xor(facc0, 16); facc0 += __shfl_xor(facc0, 32);
            facc1 += __shfl_xor(facc1, 16); facc1 += __shfl_xor(facc1, 32);
            facc2 += __shfl_xor(facc2, 16); facc2 += __shfl_xor(facc2, 32);
            facc3 += __shfl_xor(facc3, 16); facc3 += __shfl_xor(facc3, 32);
            float tot = (lq == 0) ? facc0 : (lq == 1) ? facc1 : (lq == 2) ? facc2 : facc3;
            f_lds[o * 64 + l] = tot + k32t;
        }

        // ---- o = 16 ----
        if (wq < 4) {
            const int g = wq;
            float facc = 0.0f;
            #pragma unroll 1
            for (int mt = 0; mt < 2; ++mt) {
                const int n0 = 16 * 33 + mt * 16;
                const AF A = load_A(w3hi, w3lo, n0, lm, ksl);
                const int rd = n0 + lq * 4;
                short8 Bh0, Bh1, Bl0, Bl1;
                load_B(b_hi, b_lo, g * 16 + lm, ksl, Bh0, Bh1, Bl0, Bl1);
                f32x4 aT = {0.0f, 0.0f, 0.0f, 0.0f};
                f32x4 aP = {0.0f, 0.0f, 0.0f, 0.0f};
                mfma12(A, Bh0, Bh1, Bl0, Bl1, aT, aP);
                #pragma unroll
                for (int r = 0; r < 4; ++r)
                    facc += lap_term(aT[r] + b3[rd + r], aP[r] + b3[rd + r + 561],
                                     mt * 16 + lq * 4 + r);
            }
            facc += __shfl_xor(facc, 16);
            facc += __shfl_xor(facc, 32);
            if (l < 16) f_lds[16 * 64 + g * 16 + l] = facc;
        } else if (wq == 4) {
            f16k32[l] = k32_term(W3f, b3, h1t, 16, l4);
        }
    }
    __syncthreads();

    // ---- scale + write out ----
    const int base_item = blockIdx.x * 64;
    for (int idx = tid; idx < 64 * 17; idx += 512) {
        const int li = idx / 17;
        const int o  = idx - li * 17;
        float v = f_lds[o * 64 + li];
        if (o == 16) v += f16k32[li];
        out[(base_item + li) * 17 + o] = v * scale_lds[li];
    }
}

extern "C" void kernel_launch(void* const* d_in, const int* in_sizes, int n_in,
                              void* d_out, int out_size, void* d_ws, size_t ws_size,
                              hipStream_t stream) {
    (void)in_sizes; (void)n_in; (void)out_size; (void)ws_size;
    const float* obs  = (const float*)d_in[0];
    const float* act  = (const float*)d_in[1];
    const float* ts   = (const float*)d_in[2];
    const float* Wih0 = (const float*)d_in[3];
    const float* Whh0 = (const float*)d_in[4];
    const float* bih0 = (const float*)d_in[5];
    const float* bhh0 = (const float*)d_in[6];
    const float* Wih1 = (const float*)d_in[7];
    const float* Whh1 = (const float*)d_in[8];
    const float* bih1 = (const float*)d_in[9];
    const float* bhh1 = (const float*)d_in[10];
    const float* encW = (const float*)d_in[11];
    const float* encb = (const float*)d_in[12];
    const float* W1   = (const float*)d_in[13];
    const float* b1   = (const float*)d_in[14];
    const float* W2   = (const float*)d_in[15];
    const float* b2   = (const float*)d_in[16];
    const float* W3   = (const float*)d_in[17];
    const float* b3   = (const float*)d_in[18];
    float* o_ptr  = (float*)d_out;

    // ws layout: p_act (16KB) | w3hi (1122*64 u16) | w3lo (1122*64 u16)
    float* p_act = (float*)d_ws;
    unsigned short* w3hi = (unsigned short*)((char*)d_ws + 16384);
    unsigned short* w3lo = w3hi + 1122 * 64;

    w3cvt_kernel<<<dim3((1122 * 64 + 255) / 256), dim3(256), 0, stream>>>(W3, w3hi, w3lo);
    gru_kernel<<<dim3(512), dim3(128), 0, stream>>>(
        act, Wih0, Whh0, bih0, bhh0, Wih1, Whh1, bih1, bhh1, encW, encb, p_act);
    mlp_kernel<<<dim3(512), dim3(512), 0, stream>>>(
        obs, ts, p_act, W1, b1, W2, b2, w3hi, w3lo, b3, W3, o_ptr);
}

// Round 11
// 138.014 us; speedup vs baseline: 1.7874x; 1.1699x over previous
//
#include <hip/hip_runtime.h>
#include <math.h>

#define PI_F 3.14159265358979323846f
#define PI_2F 1.57079632679489662f

typedef __attribute__((ext_vector_type(8))) short short8;
typedef __attribute__((ext_vector_type(4))) float f32x4;
#define MFMA16(A,B,C) __builtin_amdgcn_mfma_f32_16x16x32_bf16(A,B,C,0,0,0)

// ---------------- fast device math ----------------
__device__ __forceinline__ float sigm_f(float x) {
    return __fdividef(1.0f, 1.0f + __expf(-x));
}
__device__ __forceinline__ float tanh_f(float x) {
    float xc = fminf(fmaxf(x, -9.0f), 9.0f);
    float e = __expf(2.0f * xc);
    return 1.0f - __fdividef(2.0f, e + 1.0f);
}
// atan(z) for z in [0,1], max err ~1e-5 rad
__device__ __forceinline__ float atan01(float z) {
    float z2 = z * z;
    float p = fmaf(z2, -0.0117212f, 0.05265332f);
    p = fmaf(z2, p, -0.11643287f);
    p = fmaf(z2, p, 0.19354346f);
    p = fmaf(z2, p, -0.33262347f);
    p = fmaf(z2, p, 0.99997726f);
    return z * p;
}
__device__ __forceinline__ float atan_pos(float x) {
    bool big = x > 1.0f;
    float z = big ? __fdividef(1.0f, x) : x;
    float p = atan01(z);
    return big ? (PI_2F - p) : p;
}
// f32 -> bf16 (RNE) and back
__device__ __forceinline__ unsigned short f2bf(float x) {
    unsigned int u = __float_as_uint(x);
    return (unsigned short)((u + 0x7FFFu + ((u >> 16) & 1u)) >> 16);
}
__device__ __forceinline__ float bf2f(unsigned short h) {
    return __uint_as_float(((unsigned int)h) << 16);
}
__device__ __forceinline__ float lo16f(unsigned int u) { return __uint_as_float(u << 16); }
__device__ __forceinline__ float hi16f(unsigned int u) { return __uint_as_float(u & 0xFFFF0000u); }

// one Laplace series term; k = series index (sign/weight pattern period 4)
__device__ __forceinline__ float lap_term(float at, float ap, int k) {
    float th = tanh_f(at) * PI_F;
    float ph = tanh_f(ap) * (0.5f * PI_F);
    float sph = __sinf(ph), cph = __cosf(ph);
    float rdv = __fdividef(1.0f, 1.0f - sph);
    float tr = __sinf((k & 1) ? th : th + PI_2F);  // sin for odd k, cos for even
    float w = (k == 0) ? 0.5f : 1.0f;
    w = ((k + 1) & 2) ? -w : w;
    return w * tr * cph * rdv;
}

// ============================================================
// Kernel 0: split W3 (1122 x 64 f32) into bf16 hi/lo planes in ws.
// ============================================================
__global__ __launch_bounds__(256)
void w3cvt_kernel(const float* __restrict__ W3,
                  unsigned short* __restrict__ hi,
                  unsigned short* __restrict__ lo)
{
    int i = blockIdx.x * 256 + threadIdx.x;
    if (i < 1122 * 64) {
        float x = W3[i];
        unsigned short h = f2bf(x);
        hi[i] = h;
        lo[i] = f2bf(x - bf2f(h));
    }
}

// ============================================================
// Kernel 1: 2-layer GRU (unchanged from round 10).
// ============================================================
__global__ __launch_bounds__(128)
void gru_kernel(const float* __restrict__ act,
                const float* __restrict__ Wih0, const float* __restrict__ Whh0,
                const float* __restrict__ bih0, const float* __restrict__ bhh0,
                const float* __restrict__ Wih1, const float* __restrict__ Whh1,
                const float* __restrict__ bih1, const float* __restrict__ bhh1,
                const float* __restrict__ encW, const float* __restrict__ encb,
                float* __restrict__ p_out)
{
    __shared__ __align__(16) float wih0_l[6 * 128];
    __shared__ __align__(16) unsigned short whh0_p[16 * 32 * 8];
    __shared__ __align__(16) unsigned short wih1_p[16 * 32 * 8];
    __shared__ __align__(16) unsigned short whh1_p[16 * 32 * 8];
    __shared__ float enc_l[64];
    __shared__ __align__(16) float xbuf[4 * 32 * 6];
    __shared__ __align__(16) float hbuf0[4][32];
    __shared__ __align__(16) float hbuf1[4][32];

    const int tid = threadIdx.x;

    for (int idx = tid; idx < 96 * 6; idx += 128) {
        int r = idx / 6, c = idx - r * 6;
        wih0_l[c * 128 + (r & 31) * 4 + (r >> 5)] = Wih0[idx];
    }
    for (int idx = tid; idx < 96 * 32; idx += 128) {
        int r = idx >> 5, c = idx & 31;
        int g = r >> 5, j = r & 31;
        int d = ((c >> 1) * 32 + j) * 8 + g * 2 + (c & 1);
        whh0_p[d] = f2bf(Whh0[idx]);
        wih1_p[d] = f2bf(Wih1[idx]);
        whh1_p[d] = f2bf(Whh1[idx]);
    }
    if (tid < 64) {
        int o = tid >> 5, j = tid & 31;
        enc_l[j * 2 + o] = encW[o * 32 + j];
    }
    {
        const float inv3 = (1.0f / 3.0f);
        int base = blockIdx.x * (4 * 32 * 6);
        for (int idx = tid; idx < 4 * 32 * 6; idx += 128)
            xbuf[idx] = act[base + idx] * inv3;
    }
    __syncthreads();

    const int s = tid >> 5;
    const int j = tid & 31;
    const int b = blockIdx.x * 4 + s;
    const int j4 = j * 4;

    const float bi0r = bih0[j], bi0z = bih0[32 + j], bi0n = bih0[64 + j];
    const float bh0r = bhh0[j], bh0z = bhh0[32 + j], bh0n = bhh0[64 + j];
    const float bi1r = bih1[j], bi1z = bih1[32 + j], bi1n = bih1[64 + j];
    const float bh1r = bhh1[j], bh1z = bhh1[32 + j], bh1n = bhh1[64 + j];

    float* hb0 = &hbuf0[s][0];
    float* hb1 = &hbuf1[s][0];
    hb0[j] = 0.0f;
    hb1[j] = 0.0f;
    float h0 = 0.0f, h1 = 0.0f;
    const float* xs = &xbuf[s * 192];

    for (int t = 0; t < 32; ++t) {
        const float* xt = &xs[(31 - t) * 6];

        float ar = bi0r, az = bi0z, an = bi0n;
        #pragma unroll
        for (int d = 0; d < 6; ++d) {
            float xv = xt[d];
            const float4 w = *reinterpret_cast<const float4*>(&wih0_l[d * 128 + j4]);
            ar = fmaf(xv, w.x, ar); az = fmaf(xv, w.y, az); an = fmaf(xv, w.z, an);
        }
        {
            float gr0 = bh0r, gz0 = bh0z, gn0 = bh0n;
            float gr1 = 0.0f, gz1 = 0.0f, gn1 = 0.0f;
            #pragma unroll
            for (int ib = 0; ib < 32; ib += 4) {
                const float4 h4 = *reinterpret_cast<const float4*>(&hb0[ib]);
                const uint4 wA = *reinterpret_cast<const uint4*>(&whh0_p[((ib >> 1) * 32 + j) * 8]);
                const uint4 wB = *reinterpret_cast<const uint4*>(&whh0_p[((ib >> 1) * 32 + j + 32) * 8]);
                gr0 = fmaf(h4.x, lo16f(wA.x), gr0); gr1 = fmaf(h4.y, hi16f(wA.x), gr1);
                gz0 = fmaf(h4.x, lo16f(wA.y), gz0); gz1 = fmaf(h4.y, hi16f(wA.y), gz1);
                gn0 = fmaf(h4.x, lo16f(wA.z), gn0); gn1 = fmaf(h4.y, hi16f(wA.z), gn1);
                gr0 = fmaf(h4.z, lo16f(wB.x), gr0); gr1 = fmaf(h4.w, hi16f(wB.x), gr1);
                gz0 = fmaf(h4.z, lo16f(wB.y), gz0); gz1 = fmaf(h4.w, hi16f(wB.y), gz1);
                gn0 = fmaf(h4.z, lo16f(wB.z), gn0); gn1 = fmaf(h4.w, hi16f(wB.z), gn1);
            }
            float r = sigm_f(ar + gr0 + gr1);
            float z = sigm_f(az + gz0 + gz1);
            float n = tanh_f(an + r * (gn0 + gn1));
            h0 = (1.0f - z) * n + z * h0;
            hb0[j] = h0;
        }
        {
            float a1r0 = bi1r, a1z0 = bi1z, a1n0 = bi1n;
            float a1r1 = 0.0f, a1z1 = 0.0f, a1n1 = 0.0f;
            float g1r0 = bh1r, g1z0 = bh1z, g1n0 = bh1n;
            float g1r1 = 0.0f, g1z1 = 0.0f, g1n1 = 0.0f;
            #pragma unroll
            for (int ib = 0; ib < 32; ib += 4) {
                const float4 ha = *reinterpret_cast<const float4*>(&hb0[ib]);
                const float4 hg = *reinterpret_cast<const float4*>(&hb1[ib]);
                const uint4 aA = *reinterpret_cast<const uint4*>(&wih1_p[((ib >> 1) * 32 + j) * 8]);
                const uint4 aB = *reinterpret_cast<const uint4*>(&wih1_p[((ib >> 1) * 32 + j + 32) * 8]);
                const uint4 gA = *reinterpret_cast<const uint4*>(&whh1_p[((ib >> 1) * 32 + j) * 8]);
                const uint4 gB = *reinterpret_cast<const uint4*>(&whh1_p[((ib >> 1) * 32 + j + 32) * 8]);
                a1r0 = fmaf(ha.x, lo16f(aA.x), a1r0); a1r1 = fmaf(ha.y, hi16f(aA.x), a1r1);
                a1z0 = fmaf(ha.x, lo16f(aA.y), a1z0); a1z1 = fmaf(ha.y, hi16f(aA.y), a1z1);
                a1n0 = fmaf(ha.x, lo16f(aA.z), a1n0); a1n1 = fmaf(ha.y, hi16f(aA.z), a1n1);
                a1r0 = fmaf(ha.z, lo16f(aB.x), a1r0); a1r1 = fmaf(ha.w, hi16f(aB.x), a1r1);
                a1z0 = fmaf(ha.z, lo16f(aB.y), a1z0); a1z1 = fmaf(ha.w, hi16f(aB.y), a1z1);
                a1n0 = fmaf(ha.z, lo16f(aB.z), a1n0); a1n1 = fmaf(ha.w, hi16f(aB.z), a1n1);
                g1r0 = fmaf(hg.x, lo16f(gA.x), g1r0); g1r1 = fmaf(hg.y, hi16f(gA.x), g1r1);
                g1z0 = fmaf(hg.x, lo16f(gA.y), g1z0); g1z1 = fmaf(hg.y, hi16f(gA.y), g1z1);
                g1n0 = fmaf(hg.x, lo16f(gA.z), g1n0); g1n1 = fmaf(hg.y, hi16f(gA.z), g1n1);
                g1r0 = fmaf(hg.z, lo16f(gB.x), g1r0); g1r1 = fmaf(hg.w, hi16f(gB.x), g1r1);
                g1z0 = fmaf(hg.z, lo16f(gB.y), g1z0); g1z1 = fmaf(hg.w, hi16f(gB.y), g1z1);
                g1n0 = fmaf(hg.z, lo16f(gB.z), g1n0); g1n1 = fmaf(hg.w, hi16f(gB.z), g1n1);
            }
            float r1 = sigm_f(a1r0 + a1r1 + g1r0 + g1r1);
            float z1 = sigm_f(a1z0 + a1z1 + g1z0 + g1z1);
            float n1 = tanh_f(a1n0 + a1n1 + r1 * (g1n0 + g1n1));
            h1 = (1.0f - z1) * n1 + z1 * h1;
            hb1[j] = h1;
        }
    }

    float v0 = h1 * enc_l[j * 2 + 0];
    float v1 = h1 * enc_l[j * 2 + 1];
    #pragma unroll
    for (int off = 16; off > 0; off >>= 1) {
        v0 += __shfl_xor(v0, off, 32);
        v1 += __shfl_xor(v1, off, 32);
    }
    if (j == 0) {
        p_out[b * 2 + 0] = v0 + encb[0];
        p_out[b * 2 + 1] = v1 + encb[1];
    }
}

// ============================================================
// Kernel 2: per-(b,t) MLP + Laplace series.
// W3: A-reuse across 4 item-groups kept, but THETA and PHI are two
// sequential passes sharing the same 16 A-registers (halves peak
// live set -> no spill; round 10 spilled ~336 B/thread to scratch).
// fp32 h2 for the k32 VALU path lives in the dead vtp_lds region.
// ============================================================

__device__ __forceinline__ void load_B(const unsigned short* b_hi, const unsigned short* b_lo,
                                       int itm, int ksl,
                                       short8& Bh0, short8& Bh1, short8& Bl0, short8& Bl1)
{
    const int sw = (itm & 7) << 3;
    const int kx0 = ksl ^ sw;
    const int kx1 = (32 + ksl) ^ sw;
    Bh0 = *reinterpret_cast<const short8*>(&b_hi[itm * 64 + kx0]);
    Bh1 = *reinterpret_cast<const short8*>(&b_hi[itm * 64 + kx1]);
    Bl0 = *reinterpret_cast<const short8*>(&b_lo[itm * 64 + kx0]);
    Bl1 = *reinterpret_cast<const short8*>(&b_lo[itm * 64 + kx1]);
}

// epilogue for one item-group fragment: 4 series terms
__device__ __forceinline__ float lap4(f32x4 aT, f32x4 aP, const float* __restrict__ b3,
                                      int rd, int kbase)
{
    float s = 0.0f;
    #pragma unroll
    for (int r = 0; r < 4; ++r)
        s += lap_term(aT[r] + b3[rd + r], aP[r] + b3[rd + r + 561], kbase + r);
    return s;
}

// k=32 series term for one o: per-lane fp32 dot (lane = item).
__device__ __forceinline__ float k32_term(const float* __restrict__ W3f,
                                          const float* __restrict__ b3,
                                          const float* __restrict__ h2f,
                                          int o, int l4)
{
    const int rt = o * 33 + 32;
    const float* wtr = W3f + rt * 64;
    const float* wpr = W3f + (rt + 561) * 64;
    float at = b3[rt], ap = b3[rt + 561];
    #pragma unroll
    for (int c = 0; c < 16; ++c) {
        const float4 g4 = *reinterpret_cast<const float4*>(&h2f[c * 256 + l4]);
        at = fmaf(g4.x, wtr[c * 4 + 0], at);
        at = fmaf(g4.y, wtr[c * 4 + 1], at);
        at = fmaf(g4.z, wtr[c * 4 + 2], at);
        at = fmaf(g4.w, wtr[c * 4 + 3], at);
        ap = fmaf(g4.x, wpr[c * 4 + 0], ap);
        ap = fmaf(g4.y, wpr[c * 4 + 1], ap);
        ap = fmaf(g4.z, wpr[c * 4 + 2], ap);
        ap = fmaf(g4.w, wpr[c * 4 + 3], ap);
    }
    return lap_term(at, ap, 32);
}

// 6-MFMA split-bf16 accumulate of one A-stream (hi0,hi1,lo0,lo1) x one B-group
#define DOG(ACC, A0, A1, A2, A3, G) { \
    short8 Bh0, Bh1, Bl0, Bl1; \
    load_B(b_hi, b_lo, (G) * 16 + lm, ksl, Bh0, Bh1, Bl0, Bl1); \
    ACC = MFMA16(A0, Bh0, ACC); ACC = MFMA16(A1, Bh1, ACC); \
    ACC = MFMA16(A0, Bl0, ACC); ACC = MFMA16(A1, Bl1, ACC); \
    ACC = MFMA16(A2, Bh0, ACC); ACC = MFMA16(A3, Bh1, ACC); }

__global__ __launch_bounds__(512, 2)
void mlp_kernel(const float* __restrict__ obs, const float* __restrict__ ts,
                const float* __restrict__ p_act,
                const float* __restrict__ W1, const float* __restrict__ b1,
                const float* __restrict__ W2, const float* __restrict__ b2,
                const unsigned short* __restrict__ w3hi,
                const unsigned short* __restrict__ w3lo,
                const float* __restrict__ b3,
                const float* __restrict__ W3f,
                float* __restrict__ out)
{
    __shared__ __align__(16) float h1t[16 * 256];          // [i>>2][l][i&3]
    __shared__ __align__(16) unsigned short b_hi[64 * 64]; // [item][k^((item&7)<<3)]
    __shared__ __align__(16) unsigned short b_lo[64 * 64];
    __shared__ __align__(16) float vtp_lds[33 * 128];      // trig table; reused as fp32 h2
    __shared__ float f_lds[17 * 64];                       // [o][item]
    __shared__ float f16k32[64];                           // o=16 k32 terms
    __shared__ float scale_lds[64];

    float* h2f = vtp_lds;   // alias: vtp dead after H1; h2f written in H2 phase

    const int tid = threadIdx.x;
    const int wq = __builtin_amdgcn_readfirstlane(tid >> 6);  // wave id 0..7
    const int l = tid & 63;
    const int l4 = l * 4;
    const int item = blockIdx.x * 64 + l;
    const int b = item >> 4;
    const int obase = wq * 8;

    const float t = ts[item];
    const float rTc = __fdividef(0.5f, t);
    const float gamma = 0.001f + 4.6051701859880913680f * rTc;  // -ln(0.01)/Tc

    if (wq == 0) scale_lds[l] = __expf(gamma * t) * rTc;

    const float gam2 = gamma * gamma;
    const float rg = __fdividef(1.0f, gamma);
    const float pirTc = PI_F * rTc;

    // ---- trig table (once per block, k split across waves) ----
    for (int k = wq; k < 33; k += 8) {
        float sim = (float)k * pirTc;
        float vth = atan_pos(sim * rg);
        float sq = fmaf(sim, sim, gam2);
        float vph = fmaf(-2.0f, atan01(rsqrtf(sq)), PI_2F);
        vtp_lds[k * 128 + (l << 1) + 0] = vth;
        vtp_lds[k * 128 + (l << 1) + 1] = vph;
    }
    __syncthreads();

    // ---- H1: 8 outputs/wave ----
    {
        float acc[8];
        #pragma unroll
        for (int oo = 0; oo < 8; ++oo) acc[oo] = b1[obase + oo];
        const float* w1b = W1 + obase * 85;

        for (int k = 0; k < 33; ++k) {
            const float2 tp = *reinterpret_cast<const float2*>(&vtp_lds[k * 128 + (l << 1)]);
            #pragma unroll
            for (int oo = 0; oo < 8; ++oo) {
                acc[oo] = fmaf(tp.x, w1b[oo * 85 + k], acc[oo]);
                acc[oo] = fmaf(tp.y, w1b[oo * 85 + 33 + k], acc[oo]);
            }
        }
        #pragma unroll
        for (int j = 0; j < 19; ++j) {
            float pv = (j < 17) ? obs[b * 17 + j] : p_act[b * 2 + (j - 17)];
            #pragma unroll
            for (int oo = 0; oo < 8; ++oo)
                acc[oo] = fmaf(pv, w1b[oo * 85 + 66 + j], acc[oo]);
        }
        #pragma unroll
        for (int oo = 0; oo < 8; ++oo) {
            int o = obase + oo;
            h1t[(o >> 2) * 256 + l4 + (o & 3)] = tanh_f(acc[oo]);
        }
    }
    __syncthreads();   // all vtp reads done; all h1t writes done

    // ---- H2: 8 outputs/wave; bf16 hi/lo B-fragments + fp32 copy in h2f ----
    {
        float acc[8];
        #pragma unroll
        for (int oo = 0; oo < 8; ++oo) acc[oo] = b2[obase + oo];
        #pragma unroll
        for (int c = 0; c < 16; ++c) {
            const float4 g4 = *reinterpret_cast<const float4*>(&h1t[c * 256 + l4]);
            #pragma unroll
            for (int oo = 0; oo < 8; ++oo) {
                const float* wr = W2 + (obase + oo) * 64 + c * 4;
                acc[oo] = fmaf(g4.x, wr[0], acc[oo]);
                acc[oo] = fmaf(g4.y, wr[1], acc[oo]);
                acc[oo] = fmaf(g4.z, wr[2], acc[oo]);
                acc[oo] = fmaf(g4.w, wr[3], acc[oo]);
            }
        }
        const int sw = (l & 7) << 3;
        #pragma unroll
        for (int p = 0; p < 4; ++p) {
            float v0 = tanh_f(acc[2 * p + 0]);
            float v1 = tanh_f(acc[2 * p + 1]);
            // fp32 copy for the k32 VALU path (vtp region is dead now)
            int o0 = obase + 2 * p;
            h2f[((o0 + 0) >> 2) * 256 + l4 + ((o0 + 0) & 3)] = v0;
            h2f[((o0 + 1) >> 2) * 256 + l4 + ((o0 + 1) & 3)] = v1;
            unsigned short h0 = f2bf(v0), h1v = f2bf(v1);
            unsigned short q0 = f2bf(v0 - bf2f(h0)), q1 = f2bf(v1 - bf2f(h1v));
            int ksw = o0 ^ sw;
            *reinterpret_cast<unsigned int*>(&b_hi[l * 64 + ksw]) =
                (unsigned int)h0 | ((unsigned int)h1v << 16);
            *reinterpret_cast<unsigned int*>(&b_lo[l * 64 + ksw]) =
                (unsigned int)q0 | ((unsigned int)q1 << 16);
        }
    }
    __syncthreads();

    // ---- W3: MFMA, A reused across item-groups, theta/phi two-pass ----
    {
        const int lm = l & 15;
        const int lq = l >> 4;
        const int ksl = lq * 8;

        #pragma unroll 1
        for (int oo2 = 0; oo2 < 2; ++oo2) {
            const int o = wq * 2 + oo2;
            const float k32t = k32_term(W3f, b3, h2f, o, l4);
            float e0 = 0.0f, e1 = 0.0f, e2 = 0.0f, e3 = 0.0f;

            #pragma unroll 1
            for (int mt = 0; mt < 2; ++mt) {
                const int n0 = o * 33 + mt * 16;
                const unsigned short* ath = w3hi + (n0 + lm) * 64 + ksl;
                const unsigned short* atl = w3lo + (n0 + lm) * 64 + ksl;
                const unsigned short* aph = w3hi + (n0 + 561 + lm) * 64 + ksl;
                const unsigned short* apl = w3lo + (n0 + 561 + lm) * 64 + ksl;

                f32x4 accT0 = {0,0,0,0}, accT1 = {0,0,0,0}, accT2 = {0,0,0,0}, accT3 = {0,0,0,0};
                {   // theta pass — A regs live only here
                    const short8 A0 = *reinterpret_cast<const short8*>(ath);
                    const short8 A1 = *reinterpret_cast<const short8*>(ath + 32);
                    const short8 A2 = *reinterpret_cast<const short8*>(atl);
                    const short8 A3 = *reinterpret_cast<const short8*>(atl + 32);
                    DOG(accT0, A0, A1, A2, A3, 0)
                    DOG(accT1, A0, A1, A2, A3, 1)
                    DOG(accT2, A0, A1, A2, A3, 2)
                    DOG(accT3, A0, A1, A2, A3, 3)
                }
                f32x4 accP0 = {0,0,0,0}, accP1 = {0,0,0,0}, accP2 = {0,0,0,0}, accP3 = {0,0,0,0};
                {   // phi pass — reuses the same A register slots
                    const short8 A0 = *reinterpret_cast<const short8*>(aph);
                    const short8 A1 = *reinterpret_cast<const short8*>(aph + 32);
                    const short8 A2 = *reinterpret_cast<const short8*>(apl);
                    const short8 A3 = *reinterpret_cast<const short8*>(apl + 32);
                    DOG(accP0, A0, A1, A2, A3, 0)
                    DOG(accP1, A0, A1, A2, A3, 1)
                    DOG(accP2, A0, A1, A2, A3, 2)
                    DOG(accP3, A0, A1, A2, A3, 3)
                }
                const int rd = n0 + lq * 4;
                const int kbase = mt * 16 + lq * 4;
                e0 += lap4(accT0, accP0, b3, rd, kbase);
                e1 += lap4(accT1, accP1, b3, rd, kbase);
                e2 += lap4(accT2, accP2, b3, rd, kbase);
                e3 += lap4(accT3, accP3, b3, rd, kbase);
            }
            e0 += __shfl_xor(e0, 16); e0 += __shfl_xor(e0, 32);
            e1 += __shfl_xor(e1, 16); e1 += __shfl_xor(e1, 32);
            e2 += __shfl_xor(e2, 16); e2 += __shfl_xor(e2, 32);
            e3 += __shfl_xor(e3, 16); e3 += __shfl_xor(e3, 32);
            float tot = (lq == 0) ? e0 : (lq == 1) ? e1 : (lq == 2) ? e2 : e3;
            f_lds[o * 64 + l] = tot + k32t;
        }

        // ---- o = 16: waves 0-3 one item-group each; wave 4 its k32 ----
        if (wq < 4) {
            const int g = wq;
            float facc = 0.0f;
            #pragma unroll 1
            for (int mt = 0; mt < 2; ++mt) {
                const int n0 = 16 * 33 + mt * 16;
                const unsigned short* ath = w3hi + (n0 + lm) * 64 + ksl;
                const unsigned short* atl = w3lo + (n0 + lm) * 64 + ksl;
                const unsigned short* aph = w3hi + (n0 + 561 + lm) * 64 + ksl;
                const unsigned short* apl = w3lo + (n0 + 561 + lm) * 64 + ksl;

                f32x4 aT = {0,0,0,0};
                {
                    const short8 A0 = *reinterpret_cast<const short8*>(ath);
                    const short8 A1 = *reinterpret_cast<const short8*>(ath + 32);
                    const short8 A2 = *reinterpret_cast<const short8*>(atl);
                    const short8 A3 = *reinterpret_cast<const short8*>(atl + 32);
                    DOG(aT, A0, A1, A2, A3, g)
                }
                f32x4 aP = {0,0,0,0};
                {
                    const short8 A0 = *reinterpret_cast<const short8*>(aph);
                    const short8 A1 = *reinterpret_cast<const short8*>(aph + 32);
                    const short8 A2 = *reinterpret_cast<const short8*>(apl);
                    const short8 A3 = *reinterpret_cast<const short8*>(apl + 32);
                    DOG(aP, A0, A1, A2, A3, g)
                }
                facc += lap4(aT, aP, b3, n0 + lq * 4, mt * 16 + lq * 4);
            }
            facc += __shfl_xor(facc, 16);
            facc += __shfl_xor(facc, 32);
            if (l < 16) f_lds[16 * 64 + g * 16 + l] = facc;
        } else if (wq == 4) {
            f16k32[l] = k32_term(W3f, b3, h2f, 16, l4);
        }
    }
    __syncthreads();

    // ---- scale + write out ----
    const int base_item = blockIdx.x * 64;
    for (int idx = tid; idx < 64 * 17; idx += 512) {
        const int li = idx / 17;
        const int o  = idx - li * 17;
        float v = f_lds[o * 64 + li];
        if (o == 16) v += f16k32[li];
        out[(base_item + li) * 17 + o] = v * scale_lds[li];
    }
}

extern "C" void kernel_launch(void* const* d_in, const int* in_sizes, int n_in,
                              void* d_out, int out_size, void* d_ws, size_t ws_size,
                              hipStream_t stream) {
    (void)in_sizes; (void)n_in; (void)out_size; (void)ws_size;
    const float* obs  = (const float*)d_in[0];
    const float* act  = (const float*)d_in[1];
    const float* ts   = (const float*)d_in[2];
    const float* Wih0 = (const float*)d_in[3];
    const float* Whh0 = (const float*)d_in[4];
    const float* bih0 = (const float*)d_in[5];
    const float* bhh0 = (const float*)d_in[6];
    const float* Wih1 = (const float*)d_in[7];
    const float* Whh1 = (const float*)d_in[8];
    const float* bih1 = (const float*)d_in[9];
    const float* bhh1 = (const float*)d_in[10];
    const float* encW = (const float*)d_in[11];
    const float* encb = (const float*)d_in[12];
    const float* W1   = (const float*)d_in[13];
    const float* b1   = (const float*)d_in[14];
    const float* W2   = (const float*)d_in[15];
    const float* b2   = (const float*)d_in[16];
    const float* W3   = (const float*)d_in[17];
    const float* b3   = (const float*)d_in[18];
    float* o_ptr  = (float*)d_out;

    // ws layout: p_act (16KB) | w3hi (1122*64 u16) | w3lo (1122*64 u16)
    float* p_act = (float*)d_ws;
    unsigned short* w3hi = (unsigned short*)((char*)d_ws + 16384);
    unsigned short* w3lo = w3hi + 1122 * 64;

    w3cvt_kernel<<<dim3((1122 * 64 + 255) / 256), dim3(256), 0, stream>>>(W3, w3hi, w3lo);
    gru_kernel<<<dim3(512), dim3(128), 0, stream>>>(
        act, Wih0, Whh0, bih0, bhh0, Wih1, Whh1, bih1, bhh1, encW, encb, p_act);
    mlp_kernel<<<dim3(512), dim3(512), 0, stream>>>(
        obs, ts, p_act, W1, b1, W2, b2, w3hi, w3lo, b3, W3, o_ptr);
}